// Round 1
// baseline (1105.909 us; speedup 1.0000x reference)
//
#include <hip/hip_runtime.h>

// GraphEncoder: 3x GraphConv(norm='both') on fixed graph, DIM=64.
// N=65536 nodes, E=1048576 edges. Output = final h (unbatch is a reshape
// since batch_num_nodes is uniform 4096 x 16 == N).

#define N_NODES 65536
#define N_EDGES 1048576
#define DIM 64

// --- degree count: one thread per edge, float atomic increments ---
__global__ void deg_kernel(const int* __restrict__ src, const int* __restrict__ dst,
                           float* __restrict__ deg_out, float* __restrict__ deg_in) {
    int e = blockIdx.x * blockDim.x + threadIdx.x;
    if (e < N_EDGES) {
        atomicAdd(&deg_out[src[e]], 1.0f);
        atomicAdd(&deg_in[dst[e]], 1.0f);
    }
}

// --- convert degree -> rsqrt(clip(deg,1)) in place (both arrays, 2N contiguous) ---
__global__ void rsqrt_kernel(float* __restrict__ deg) {
    int i = blockIdx.x * blockDim.x + threadIdx.x;
    if (i < 2 * N_NODES) {
        float d = deg[i];
        deg[i] = rsqrtf(d < 1.0f ? 1.0f : d);
    }
}

// --- fused gather * rsqrt(deg_out[src]) -> atomicAdd scatter to agg[dst] ---
// One wave (64 lanes) per edge; lane = feature dim. Gather read and atomic
// destination are both 64 consecutive floats -> coalesced.
__global__ void scatter_kernel(const float* __restrict__ x, const int* __restrict__ src,
                               const int* __restrict__ dst, const float* __restrict__ rs_out,
                               float* __restrict__ agg) {
    int tid = blockIdx.x * blockDim.x + threadIdx.x;
    int e = tid >> 6;
    int lane = tid & 63;
    if (e < N_EDGES) {
        int s = src[e];      // wave-uniform (all lanes same addr -> broadcast)
        int d = dst[e];
        float v = x[s * DIM + lane] * rs_out[s];
        atomicAdd(&agg[d * DIM + lane], v);
    }
}

// --- out[n][j] = relu?( sum_k (agg[n][k]*rs_in[n]) * W[k][j] + b[j] ) ---
// One wave per node; W staged in LDS; row broadcast via __shfl.
template<bool RELU>
__global__ void matmul_kernel(const float* __restrict__ agg, const float* __restrict__ rs_in,
                              const float* __restrict__ W, const float* __restrict__ b,
                              float* __restrict__ out) {
    __shared__ float Ws[DIM * DIM];
    __shared__ float bs[DIM];
    for (int i = threadIdx.x; i < DIM * DIM; i += blockDim.x) Ws[i] = W[i];
    if (threadIdx.x < DIM) bs[threadIdx.x] = b[threadIdx.x];
    __syncthreads();
    int wave = (int)((blockIdx.x * blockDim.x + threadIdx.x) >> 6);
    int lane = threadIdx.x & 63;
    if (wave < N_NODES) {
        float r = agg[wave * DIM + lane] * rs_in[wave];
        float acc = bs[lane];
        #pragma unroll
        for (int k = 0; k < DIM; k++) {
            // Ws read: 64 consecutive floats per k -> 2 lanes/bank, conflict-free
            acc += __shfl(r, k, 64) * Ws[k * DIM + lane];
        }
        if (RELU) acc = acc < 0.0f ? 0.0f : acc;
        out[wave * DIM + lane] = acc;
    }
}

extern "C" void kernel_launch(void* const* d_in, const int* in_sizes, int n_in,
                              void* d_out, int out_size, void* d_ws, size_t ws_size,
                              hipStream_t stream) {
    const float* x   = (const float*)d_in[0];          // node_feats [N, 64]
    const int*   ei  = (const int*)d_in[1];            // edge_index [2, E]
    const int*   src = ei;
    const int*   dst = ei + N_EDGES;
    // d_in[2] = batch_num_nodes (uniform -> unbatch is identity reshape)
    const float* W1 = (const float*)d_in[3];
    const float* b1 = (const float*)d_in[4];
    const float* W2 = (const float*)d_in[5];
    const float* b2 = (const float*)d_in[6];
    const float* W3 = (const float*)d_in[7];
    const float* b3 = (const float*)d_in[8];
    float* out = (float*)d_out;

    // workspace layout: [deg_out|deg_in] (2N f32) | bufA (N*64 f32) | bufB (N*64 f32)
    char* ws = (char*)d_ws;
    float* deg    = (float*)ws;                 // becomes rs_out / rs_in after rsqrt
    float* rs_out = deg;
    float* rs_in  = deg + N_NODES;
    float* bufA   = (float*)(ws + (size_t)2 * N_NODES * sizeof(float));
    float* bufB   = bufA + (size_t)N_NODES * DIM;

    const size_t feat_bytes = (size_t)N_NODES * DIM * sizeof(float);
    const int scatter_blocks = (N_EDGES * 64) / 256;   // 262144
    const int matmul_blocks  = (N_NODES * 64) / 256;   // 16384

    // degrees (graph is fixed across layers)
    hipMemsetAsync(deg, 0, (size_t)2 * N_NODES * sizeof(float), stream);
    deg_kernel<<<N_EDGES / 256, 256, 0, stream>>>(src, dst, deg, deg + N_NODES);
    rsqrt_kernel<<<(2 * N_NODES) / 256, 256, 0, stream>>>(deg);

    // layer 1: x -> bufA (agg) -> bufB (relu(.@W1+b1))
    hipMemsetAsync(bufA, 0, feat_bytes, stream);
    scatter_kernel<<<scatter_blocks, 256, 0, stream>>>(x, src, dst, rs_out, bufA);
    matmul_kernel<true><<<matmul_blocks, 256, 0, stream>>>(bufA, rs_in, W1, b1, bufB);

    // layer 2: bufB -> bufA -> bufB
    hipMemsetAsync(bufA, 0, feat_bytes, stream);
    scatter_kernel<<<scatter_blocks, 256, 0, stream>>>(bufB, src, dst, rs_out, bufA);
    matmul_kernel<true><<<matmul_blocks, 256, 0, stream>>>(bufA, rs_in, W2, b2, bufB);

    // layer 3: bufB -> bufA -> d_out (no relu)
    hipMemsetAsync(bufA, 0, feat_bytes, stream);
    scatter_kernel<<<scatter_blocks, 256, 0, stream>>>(bufB, src, dst, rs_out, bufA);
    matmul_kernel<false><<<matmul_blocks, 256, 0, stream>>>(bufA, rs_in, W3, b3, out);
}

// Round 2
// 706.169 us; speedup vs baseline: 1.5661x; 1.5661x over previous
//
#include <hip/hip_runtime.h>

// GraphEncoder: 3x GraphConv(norm='both'), DIM=64, fixed graph.
// Strategy: build dst-CSR once per launch (int atomics only), then each layer
// is ONE fused kernel: gather x[src]*rs_out[src] -> register acc -> *rs_in ->
// shuffle-broadcast 64x64 matmul (+bias, relu) -> single coalesced write.
// Zero float atomics, zero intermediate agg buffers, zero feature memsets.

#define N_NODES 65536
#define N_EDGES 1048576
#define DIM 64

// --- degree count (int atomics) ---
__global__ void deg_kernel(const int* __restrict__ src, const int* __restrict__ dst,
                           int* __restrict__ deg_out, int* __restrict__ deg_in) {
    int e = blockIdx.x * blockDim.x + threadIdx.x;
    if (e < N_EDGES) {
        atomicAdd(&deg_out[src[e]], 1);
        atomicAdd(&deg_in[dst[e]], 1);
    }
}

// --- single-block exclusive scan of deg_in[0..N) -> row_start[0..N], cursor copy ---
// 1024 threads, each owns 64 contiguous elements. Hillis-Steele over thread sums.
__global__ void scan_kernel(const int* __restrict__ deg_in, int* __restrict__ row_start,
                            int* __restrict__ cursor) {
    __shared__ int s[1024];
    int t = threadIdx.x;
    int base = t * 64;
    int sum = 0;
    #pragma unroll 4
    for (int i = 0; i < 64; i++) sum += deg_in[base + i];
    s[t] = sum;
    __syncthreads();
    for (int off = 1; off < 1024; off <<= 1) {
        int v = (t >= off) ? s[t - off] : 0;
        __syncthreads();
        s[t] += v;
        __syncthreads();
    }
    int run = s[t] - sum;   // exclusive prefix of this thread's chunk
    for (int i = 0; i < 64; i++) {
        row_start[base + i] = run;
        cursor[base + i] = run;
        run += deg_in[base + i];
    }
    if (t == 1023) row_start[N_NODES] = run;  // == N_EDGES
}

// --- rsqrt(clip(deg,1)) for both deg arrays (2N contiguous ints -> floats) ---
__global__ void rsqrt_kernel(const int* __restrict__ deg, float* __restrict__ rs) {
    int i = blockIdx.x * blockDim.x + threadIdx.x;
    if (i < 2 * N_NODES) {
        int d = deg[i];
        rs[i] = rsqrtf(d < 1 ? 1.0f : (float)d);
    }
}

// --- CSR fill: csr_src[cursor[dst]++] = src ---
__global__ void fill_kernel(const int* __restrict__ src, const int* __restrict__ dst,
                            int* __restrict__ cursor, int* __restrict__ csr_src) {
    int e = blockIdx.x * blockDim.x + threadIdx.x;
    if (e < N_EDGES) {
        int pos = atomicAdd(&cursor[dst[e]], 1);
        csr_src[pos] = src[e];
    }
}

// --- fused layer: aggregate + sym-norm + 64x64 matmul + bias (+relu) ---
// One wave per dst node; lane = feature dim.
template<bool RELU>
__global__ void fused_layer(const float* __restrict__ x, const int* __restrict__ row_start,
                            const int* __restrict__ csr_src, const float* __restrict__ rs_out,
                            const float* __restrict__ rs_in, const float* __restrict__ W,
                            const float* __restrict__ b, float* __restrict__ out) {
    __shared__ float Ws[DIM * DIM];
    __shared__ float bs[DIM];
    for (int i = threadIdx.x; i < DIM * DIM; i += blockDim.x) Ws[i] = W[i];
    if (threadIdx.x < DIM) bs[threadIdx.x] = b[threadIdx.x];
    __syncthreads();

    int node = (int)((blockIdx.x * blockDim.x + threadIdx.x) >> 6);
    int lane = threadIdx.x & 63;
    if (node >= N_NODES) return;

    int beg = row_start[node];
    int end = row_start[node + 1];
    float acc = 0.0f;
    for (int k = beg; k < end; k++) {
        int s = csr_src[k];                       // wave-uniform broadcast
        acc += x[s * DIM + lane] * rs_out[s];     // 256B contiguous gather
    }
    acc *= rs_in[node];

    float o = bs[lane];
    #pragma unroll
    for (int k = 0; k < DIM; k++) {
        o += __shfl(acc, k, 64) * Ws[k * DIM + lane];  // 2 lanes/bank: free
    }
    if (RELU) o = o < 0.0f ? 0.0f : o;
    out[node * DIM + lane] = o;
}

extern "C" void kernel_launch(void* const* d_in, const int* in_sizes, int n_in,
                              void* d_out, int out_size, void* d_ws, size_t ws_size,
                              hipStream_t stream) {
    const float* x   = (const float*)d_in[0];
    const int*   ei  = (const int*)d_in[1];
    const int*   src = ei;
    const int*   dst = ei + N_EDGES;
    const float* W1 = (const float*)d_in[3];
    const float* b1 = (const float*)d_in[4];
    const float* W2 = (const float*)d_in[5];
    const float* b2 = (const float*)d_in[6];
    const float* W3 = (const float*)d_in[7];
    const float* b3 = (const float*)d_in[8];
    float* out = (float*)d_out;

    // workspace layout
    char* ws = (char*)d_ws;
    int*   deg_i     = (int*)ws;                                   // [2N] out|in
    int*   deg_out_i = deg_i;
    int*   deg_in_i  = deg_i + N_NODES;
    float* rs        = (float*)(deg_i + 2 * N_NODES);              // [2N] out|in
    float* rs_out    = rs;
    float* rs_in     = rs + N_NODES;
    int*   row_start = (int*)(rs + 2 * N_NODES);                   // [N+1]
    int*   cursor    = row_start + (N_NODES + 1);                  // [N]
    int*   csr_src   = cursor + N_NODES;                           // [E]
    float* bufA      = (float*)(csr_src + N_EDGES);                // [N*64]
    float* bufB      = bufA + (size_t)N_NODES * DIM;               // [N*64]

    const int eb = N_EDGES / 256;           // 4096 blocks
    const int fb = (N_NODES * 64) / 256;    // 16384 blocks

    // CSR + norm prep (graph fixed across layers)
    hipMemsetAsync(deg_i, 0, (size_t)2 * N_NODES * sizeof(int), stream);
    deg_kernel<<<eb, 256, 0, stream>>>(src, dst, deg_out_i, deg_in_i);
    scan_kernel<<<1, 1024, 0, stream>>>(deg_in_i, row_start, cursor);
    rsqrt_kernel<<<(2 * N_NODES) / 256, 256, 0, stream>>>(deg_i, rs);
    fill_kernel<<<eb, 256, 0, stream>>>(src, dst, cursor, csr_src);

    // 3 fused layers: x -> bufA -> bufB -> out
    fused_layer<true ><<<fb, 256, 0, stream>>>(x,    row_start, csr_src, rs_out, rs_in, W1, b1, bufA);
    fused_layer<true ><<<fb, 256, 0, stream>>>(bufA, row_start, csr_src, rs_out, rs_in, W2, b2, bufB);
    fused_layer<false><<<fb, 256, 0, stream>>>(bufB, row_start, csr_src, rs_out, rs_in, W3, b3, out);
}

// Round 3
// 595.998 us; speedup vs baseline: 1.8556x; 1.1849x over previous
//
#include <hip/hip_runtime.h>

// GraphEncoder: 3x GraphConv(norm='both'), DIM=64, fixed graph.
// R3: latency-bound gather loop -> unroll x8 for memory-level parallelism;
// pre-scaled feature buffers (x * rs_out folded into previous epilogue) so the
// gather body is a single load+add per edge.

#define N_NODES 65536
#define N_EDGES 1048576
#define DIM 64

// --- degree count (int atomics) ---
__global__ void deg_kernel(const int* __restrict__ src, const int* __restrict__ dst,
                           int* __restrict__ deg_out, int* __restrict__ deg_in) {
    int e = blockIdx.x * blockDim.x + threadIdx.x;
    if (e < N_EDGES) {
        atomicAdd(&deg_out[src[e]], 1);
        atomicAdd(&deg_in[dst[e]], 1);
    }
}

// --- single-block exclusive scan of deg_in -> row_start[N+1], cursor copy ---
__global__ void scan_kernel(const int* __restrict__ deg_in, int* __restrict__ row_start,
                            int* __restrict__ cursor) {
    __shared__ int s[1024];
    int t = threadIdx.x;
    int base = t * 64;
    int sum = 0;
    #pragma unroll 4
    for (int i = 0; i < 64; i++) sum += deg_in[base + i];
    s[t] = sum;
    __syncthreads();
    for (int off = 1; off < 1024; off <<= 1) {
        int v = (t >= off) ? s[t - off] : 0;
        __syncthreads();
        s[t] += v;
        __syncthreads();
    }
    int run = s[t] - sum;
    for (int i = 0; i < 64; i++) {
        row_start[base + i] = run;
        cursor[base + i] = run;
        run += deg_in[base + i];
    }
    if (t == 1023) row_start[N_NODES] = run;
}

// --- rsqrt(clip(deg,1)) for both deg arrays ---
__global__ void rsqrt_kernel(const int* __restrict__ deg, float* __restrict__ rs) {
    int i = blockIdx.x * blockDim.x + threadIdx.x;
    if (i < 2 * N_NODES) {
        int d = deg[i];
        rs[i] = rsqrtf(d < 1 ? 1.0f : (float)d);
    }
}

// --- CSR fill: csr_src[cursor[dst]++] = src ---
__global__ void fill_kernel(const int* __restrict__ src, const int* __restrict__ dst,
                            int* __restrict__ cursor, int* __restrict__ csr_src) {
    int e = blockIdx.x * blockDim.x + threadIdx.x;
    if (e < N_EDGES) {
        int pos = atomicAdd(&cursor[dst[e]], 1);
        csr_src[pos] = src[e];
    }
}

// --- prescale: xs[n] = x[n] * rs_out[n]  (one wave per node) ---
__global__ void prescale_kernel(const float* __restrict__ x, const float* __restrict__ rs_out,
                                float* __restrict__ xs) {
    int tid = blockIdx.x * blockDim.x + threadIdx.x;
    int node = tid >> 6;
    int lane = tid & 63;
    xs[node * DIM + lane] = x[node * DIM + lane] * rs_out[node];
}

// --- fused layer: gather(pre-scaled) + rs_in + 64x64 matmul + bias
//     epilogue: SCALE_OUT ? relu(o)*rs_out -> next-layer buffer
//               else        o (no relu)    -> final output
template<bool SCALE_OUT>
__global__ void fused_layer(const float* __restrict__ xs, const int* __restrict__ row_start,
                            const int* __restrict__ csr_src, const float* __restrict__ rs_out,
                            const float* __restrict__ rs_in, const float* __restrict__ W,
                            const float* __restrict__ b, float* __restrict__ out) {
    __shared__ float Ws[DIM * DIM];
    __shared__ float bs[DIM];
    for (int i = threadIdx.x; i < DIM * DIM; i += blockDim.x) Ws[i] = W[i];
    if (threadIdx.x < DIM) bs[threadIdx.x] = b[threadIdx.x];
    __syncthreads();

    int node = (int)((blockIdx.x * blockDim.x + threadIdx.x) >> 6);
    int lane = threadIdx.x & 63;
    if (node >= N_NODES) return;

    int beg = row_start[node];
    int end = row_start[node + 1];

    // unrolled x8: 8 independent index loads, then 8 gathers in flight
    float acc = 0.0f;
    int k = beg;
    for (; k + 8 <= end; k += 8) {
        int s0 = csr_src[k + 0], s1 = csr_src[k + 1];
        int s2 = csr_src[k + 2], s3 = csr_src[k + 3];
        int s4 = csr_src[k + 4], s5 = csr_src[k + 5];
        int s6 = csr_src[k + 6], s7 = csr_src[k + 7];
        float v0 = xs[s0 * DIM + lane], v1 = xs[s1 * DIM + lane];
        float v2 = xs[s2 * DIM + lane], v3 = xs[s3 * DIM + lane];
        float v4 = xs[s4 * DIM + lane], v5 = xs[s5 * DIM + lane];
        float v6 = xs[s6 * DIM + lane], v7 = xs[s7 * DIM + lane];
        acc += ((v0 + v1) + (v2 + v3)) + ((v4 + v5) + (v6 + v7));
    }
    for (; k < end; k++) {
        acc += xs[csr_src[k] * DIM + lane];
    }
    acc *= rs_in[node];

    float o = bs[lane];
    #pragma unroll
    for (int kk = 0; kk < DIM; kk++) {
        o += __shfl(acc, kk, 64) * Ws[kk * DIM + lane];
    }
    if (SCALE_OUT) {
        o = o < 0.0f ? 0.0f : o;          // relu
        o *= rs_out[node];                // fold next layer's src scaling
    }
    out[node * DIM + lane] = o;
}

extern "C" void kernel_launch(void* const* d_in, const int* in_sizes, int n_in,
                              void* d_out, int out_size, void* d_ws, size_t ws_size,
                              hipStream_t stream) {
    const float* x   = (const float*)d_in[0];
    const int*   ei  = (const int*)d_in[1];
    const int*   src = ei;
    const int*   dst = ei + N_EDGES;
    const float* W1 = (const float*)d_in[3];
    const float* b1 = (const float*)d_in[4];
    const float* W2 = (const float*)d_in[5];
    const float* b2 = (const float*)d_in[6];
    const float* W3 = (const float*)d_in[7];
    const float* b3 = (const float*)d_in[8];
    float* out = (float*)d_out;

    // workspace layout
    char* ws = (char*)d_ws;
    int*   deg_i     = (int*)ws;                                   // [2N]
    int*   deg_out_i = deg_i;
    int*   deg_in_i  = deg_i + N_NODES;
    float* rs        = (float*)(deg_i + 2 * N_NODES);              // [2N]
    float* rs_out    = rs;
    float* rs_in     = rs + N_NODES;
    int*   row_start = (int*)(rs + 2 * N_NODES);                   // [N+1]
    int*   cursor    = row_start + (N_NODES + 1);                  // [N]
    int*   csr_src   = cursor + N_NODES;                           // [E]
    float* bufA      = (float*)(csr_src + N_EDGES);                // [N*64]
    float* bufB      = bufA + (size_t)N_NODES * DIM;               // [N*64]

    const int eb = N_EDGES / 256;           // 4096
    const int fb = (N_NODES * 64) / 256;    // 16384

    // CSR + norm prep (graph fixed across layers)
    hipMemsetAsync(deg_i, 0, (size_t)2 * N_NODES * sizeof(int), stream);
    deg_kernel<<<eb, 256, 0, stream>>>(src, dst, deg_out_i, deg_in_i);
    scan_kernel<<<1, 1024, 0, stream>>>(deg_in_i, row_start, cursor);
    rsqrt_kernel<<<(2 * N_NODES) / 256, 256, 0, stream>>>(deg_i, rs);
    fill_kernel<<<eb, 256, 0, stream>>>(src, dst, cursor, csr_src);

    // prescale layer-1 input: bufA = x * rs_out
    prescale_kernel<<<fb, 256, 0, stream>>>(x, rs_out, bufA);

    // layers: bufA -> bufB(scaled) -> bufA(scaled) -> d_out (unscaled, no relu)
    fused_layer<true ><<<fb, 256, 0, stream>>>(bufA, row_start, csr_src, rs_out, rs_in, W1, b1, bufB);
    fused_layer<true ><<<fb, 256, 0, stream>>>(bufB, row_start, csr_src, rs_out, rs_in, W2, b2, bufA);
    fused_layer<false><<<fb, 256, 0, stream>>>(bufA, row_start, csr_src, rs_out, rs_in, W3, b3, out);
}

// Round 4
// 433.781 us; speedup vs baseline: 2.5495x; 1.3740x over previous
//
#include <hip/hip_runtime.h>

// GraphEncoder: 3x GraphConv(norm='both'), DIM=64, fixed graph.
// R4: fused layer restructured to 4 nodes/wave, 16 lanes/node, float4/lane.
// -> 1KB per gather instruction (16B/lane), 4 independent edge streams/wave,
//    8KB in flight per wave. Prep: parallel 3-phase scan, int4 edge reads.

#define N_NODES 65536
#define N_EDGES 1048576
#define DIM 64
#define UNROLL 8

// --- degree count (int atomics), 4 edges per thread ---
__global__ void deg_kernel(const int4* __restrict__ src4, const int4* __restrict__ dst4,
                           int* __restrict__ deg_out, int* __restrict__ deg_in) {
    int i = blockIdx.x * blockDim.x + threadIdx.x;   // < N_EDGES/4
    int4 s = src4[i];
    int4 d = dst4[i];
    atomicAdd(&deg_out[s.x], 1); atomicAdd(&deg_out[s.y], 1);
    atomicAdd(&deg_out[s.z], 1); atomicAdd(&deg_out[s.w], 1);
    atomicAdd(&deg_in[d.x], 1);  atomicAdd(&deg_in[d.y], 1);
    atomicAdd(&deg_in[d.z], 1);  atomicAdd(&deg_in[d.w], 1);
}

// --- 3-phase exclusive scan of deg_in[0..N) ---
__global__ void scan1(const int* __restrict__ deg_in, int* __restrict__ partials) {
    __shared__ int red[256];
    red[threadIdx.x] = deg_in[blockIdx.x * 256 + threadIdx.x];
    __syncthreads();
    for (int off = 128; off > 0; off >>= 1) {
        if (threadIdx.x < off) red[threadIdx.x] += red[threadIdx.x + off];
        __syncthreads();
    }
    if (threadIdx.x == 0) partials[blockIdx.x] = red[0];
}
__global__ void scan2(int* __restrict__ partials) {   // in-place exclusive scan of 256
    __shared__ int s[256];
    int t = threadIdx.x;
    int mine = partials[t];
    s[t] = mine;
    __syncthreads();
    for (int off = 1; off < 256; off <<= 1) {
        int v = (t >= off) ? s[t - off] : 0;
        __syncthreads();
        s[t] += v;
        __syncthreads();
    }
    partials[t] = s[t] - mine;
}
__global__ void scan3(const int* __restrict__ deg_in, const int* __restrict__ partials,
                      int* __restrict__ row_start, int* __restrict__ cursor) {
    __shared__ int s[256];
    int t = threadIdx.x;
    int i = blockIdx.x * 256 + t;
    int d = deg_in[i];
    s[t] = d;
    __syncthreads();
    for (int off = 1; off < 256; off <<= 1) {
        int v = (t >= off) ? s[t - off] : 0;
        __syncthreads();
        s[t] += v;
        __syncthreads();
    }
    int val = partials[blockIdx.x] + s[t] - d;   // exclusive prefix
    row_start[i] = val;
    cursor[i] = val;
    if (i == N_NODES - 1) row_start[N_NODES] = val + d;   // == N_EDGES
}

// --- rsqrt(clip(deg,1)) for both deg arrays ---
__global__ void rsqrt_kernel(const int* __restrict__ deg, float* __restrict__ rs) {
    int i = blockIdx.x * blockDim.x + threadIdx.x;
    if (i < 2 * N_NODES) {
        int d = deg[i];
        rs[i] = rsqrtf(d < 1 ? 1.0f : (float)d);
    }
}

// --- CSR fill, 4 edges per thread ---
__global__ void fill_kernel(const int4* __restrict__ src4, const int4* __restrict__ dst4,
                            int* __restrict__ cursor, int* __restrict__ csr_src) {
    int i = blockIdx.x * blockDim.x + threadIdx.x;
    int4 s = src4[i];
    int4 d = dst4[i];
    csr_src[atomicAdd(&cursor[d.x], 1)] = s.x;
    csr_src[atomicAdd(&cursor[d.y], 1)] = s.y;
    csr_src[atomicAdd(&cursor[d.z], 1)] = s.z;
    csr_src[atomicAdd(&cursor[d.w], 1)] = s.w;
}

// --- prescale: xs[n] = x[n] * rs_out[n] ---
__global__ void prescale_kernel(const float4* __restrict__ x4, const float* __restrict__ rs_out,
                                float4* __restrict__ xs4) {
    int i = blockIdx.x * blockDim.x + threadIdx.x;   // < N*16
    int node = i >> 4;
    float r = rs_out[node];
    float4 v = x4[i];
    v.x *= r; v.y *= r; v.z *= r; v.w *= r;
    xs4[i] = v;
}

// --- fused layer: 4 nodes per wave, 16 lanes per node, float4 per lane ---
template<bool SCALE_OUT>
__global__ void fused_layer(const float4* __restrict__ xs4, const int* __restrict__ row_start,
                            const int* __restrict__ csr_src, const float* __restrict__ rs_out,
                            const float* __restrict__ rs_in, const float* __restrict__ W,
                            const float* __restrict__ b, float4* __restrict__ out4) {
    __shared__ float4 Ws4[DIM * 16];   // row k: 16 float4 (cols 4l..4l+3)
    __shared__ float4 bs4[16];
    {
        const float4* Wg = (const float4*)W;
        for (int i = threadIdx.x; i < DIM * 16; i += blockDim.x) Ws4[i] = Wg[i];
        if (threadIdx.x < 16) bs4[threadIdx.x] = ((const float4*)b)[threadIdx.x];
    }
    __syncthreads();

    int wave_id = threadIdx.x >> 6;                 // 0..3
    int lane = threadIdx.x & 63;
    int g = lane >> 4;                              // edge-stream group 0..3
    int l = lane & 15;                              // lane in group
    int node = blockIdx.x * 16 + wave_id * 4 + g;   // block covers 16 nodes

    int beg = row_start[node];
    int end = row_start[node + 1];

    float4 acc = make_float4(0.f, 0.f, 0.f, 0.f);
    int k = beg;
    for (; k + UNROLL <= end; k += UNROLL) {        // divergent trip count: exec-masked
        int s[UNROLL];
        #pragma unroll
        for (int j = 0; j < UNROLL; j++) s[j] = csr_src[k + j];
        float4 v[UNROLL];
        #pragma unroll
        for (int j = 0; j < UNROLL; j++) v[j] = xs4[s[j] * 16 + l];
        #pragma unroll
        for (int j = 0; j < UNROLL; j++) {
            acc.x += v[j].x; acc.y += v[j].y; acc.z += v[j].z; acc.w += v[j].w;
        }
    }
    for (; k < end; k++) {
        float4 v = xs4[csr_src[k] * 16 + l];
        acc.x += v.x; acc.y += v.y; acc.z += v.z; acc.w += v.w;
    }
    float ri = rs_in[node];
    acc.x *= ri; acc.y *= ri; acc.z *= ri; acc.w *= ri;

    // matmul: o[4l+c] = b[4l+c] + sum_k acc[k] * W[k][4l+c]
    float4 o = bs4[l];
    int gbase = g << 4;
    #pragma unroll
    for (int m = 0; m < 16; m++) {
        float ax = __shfl(acc.x, gbase + m, 64);    // features 4m..4m+3
        float ay = __shfl(acc.y, gbase + m, 64);
        float az = __shfl(acc.z, gbase + m, 64);
        float aw = __shfl(acc.w, gbase + m, 64);
        float4 w0 = Ws4[(4 * m + 0) * 16 + l];      // same addr in all 4 groups: broadcast
        float4 w1 = Ws4[(4 * m + 1) * 16 + l];
        float4 w2 = Ws4[(4 * m + 2) * 16 + l];
        float4 w3 = Ws4[(4 * m + 3) * 16 + l];
        o.x += ax * w0.x + ay * w1.x + az * w2.x + aw * w3.x;
        o.y += ax * w0.y + ay * w1.y + az * w2.y + aw * w3.y;
        o.z += ax * w0.z + ay * w1.z + az * w2.z + aw * w3.z;
        o.w += ax * w0.w + ay * w1.w + az * w2.w + aw * w3.w;
    }
    if (SCALE_OUT) {
        float ro = rs_out[node];
        o.x = (o.x < 0.f ? 0.f : o.x) * ro;
        o.y = (o.y < 0.f ? 0.f : o.y) * ro;
        o.z = (o.z < 0.f ? 0.f : o.z) * ro;
        o.w = (o.w < 0.f ? 0.f : o.w) * ro;
    }
    out4[node * 16 + l] = o;
}

extern "C" void kernel_launch(void* const* d_in, const int* in_sizes, int n_in,
                              void* d_out, int out_size, void* d_ws, size_t ws_size,
                              hipStream_t stream) {
    const float* x   = (const float*)d_in[0];
    const int*   ei  = (const int*)d_in[1];
    const int4*  src4 = (const int4*)ei;
    const int4*  dst4 = (const int4*)(ei + N_EDGES);
    const float* W1 = (const float*)d_in[3];
    const float* b1 = (const float*)d_in[4];
    const float* W2 = (const float*)d_in[5];
    const float* b2 = (const float*)d_in[6];
    const float* W3 = (const float*)d_in[7];
    const float* b3 = (const float*)d_in[8];
    float* out = (float*)d_out;

    // workspace layout
    char* ws = (char*)d_ws;
    int*   deg_i     = (int*)ws;                                   // [2N]
    int*   deg_in_i  = deg_i + N_NODES;
    float* rs        = (float*)(deg_i + 2 * N_NODES);              // [2N]
    float* rs_out    = rs;
    float* rs_in     = rs + N_NODES;
    int*   row_start = (int*)(rs + 2 * N_NODES);                   // [N+1]
    int*   cursor    = row_start + (N_NODES + 1);                  // [N]
    int*   partials  = cursor + N_NODES;                           // [256]
    int*   csr_src   = partials + 256;                             // [E]
    float* bufA      = (float*)(csr_src + N_EDGES);                // [N*64]
    float* bufB      = bufA + (size_t)N_NODES * DIM;               // [N*64]

    const int e4b = (N_EDGES / 4) / 256;        // 1024
    const int fb  = N_NODES / 16;               // 4096 blocks, 256 thr, 4 nodes/wave

    // CSR + norm prep (graph fixed across layers)
    hipMemsetAsync(deg_i, 0, (size_t)2 * N_NODES * sizeof(int), stream);
    deg_kernel<<<e4b, 256, 0, stream>>>(src4, dst4, deg_i, deg_in_i);
    scan1<<<256, 256, 0, stream>>>(deg_in_i, partials);
    scan2<<<1, 256, 0, stream>>>(partials);
    scan3<<<256, 256, 0, stream>>>(deg_in_i, partials, row_start, cursor);
    rsqrt_kernel<<<(2 * N_NODES) / 256, 256, 0, stream>>>(deg_i, rs);
    fill_kernel<<<e4b, 256, 0, stream>>>(src4, dst4, cursor, csr_src);

    // prescale layer-1 input: bufA = x * rs_out
    prescale_kernel<<<(N_NODES * 16) / 256, 256, 0, stream>>>((const float4*)x, rs_out, (float4*)bufA);

    // layers: bufA -> bufB(scaled) -> bufA(scaled) -> d_out (unscaled, no relu)
    fused_layer<true ><<<fb, 256, 0, stream>>>((const float4*)bufA, row_start, csr_src, rs_out, rs_in, W1, b1, (float4*)bufB);
    fused_layer<true ><<<fb, 256, 0, stream>>>((const float4*)bufB, row_start, csr_src, rs_out, rs_in, W2, b2, (float4*)bufA);
    fused_layer<false><<<fb, 256, 0, stream>>>((const float4*)bufA, row_start, csr_src, rs_out, rs_in, W3, b3, (float4*)out);
}

// Round 5
// 411.372 us; speedup vs baseline: 2.6883x; 1.0545x over previous
//
#include <hip/hip_runtime.h>

// GraphEncoder: 3x GraphConv(norm='both'), DIM=64, fixed graph.
// R5: prep rebuilt without scattered global atomics.
//  - CSR: 256-way counting sort by dst>>8 (LDS hist -> scan -> rank scatter of
//    packed src|dlow words), then per-bucket LDS-cursor pass -> csr_src.
//    deg_in falls out of the bucket histograms free.
//  - deg_out: partial LDS histograms (4 ranges x 16 chunks) + dense reduce.
//  All scatter writes are plain stores into small windows (L2 write-back),
//  zero scattered device atomics. Layers unchanged from R4.

#define N_NODES 65536
#define N_EDGES 1048576
#define DIM 64
#define UNROLL 8

#define PCHUNKS 64
#define EPC (N_EDGES / PCHUNKS)       // 16384 edges per partition chunk
#define RANGES 4
#define RBINS (N_NODES / RANGES)      // 16384 bins per range (64KB LDS)
#define HCHUNKS 16
#define EHC (N_EDGES / HCHUNKS)       // 65536 edges per hist chunk

// --- partition phase 1: per-(bucket,chunk) histogram of dst>>8 ---
__global__ void part_hist(const int* __restrict__ dst, int* __restrict__ block_hist) {
    __shared__ int h[256];
    h[threadIdx.x] = 0;
    __syncthreads();
    int base = blockIdx.x * EPC;
    for (int i = threadIdx.x; i < EPC; i += 256)
        atomicAdd(&h[dst[base + i] >> 8], 1);
    __syncthreads();
    block_hist[threadIdx.x * PCHUNKS + blockIdx.x] = h[threadIdx.x];  // [bucket][chunk]
}

// --- partition phase 2: exclusive scan of 16384 (bucket-major) ---
__global__ void part_scan(const int* __restrict__ bh, int* __restrict__ so) {
    __shared__ int s[1024];
    int t = threadIdx.x;
    int base = t * 16;
    int v[16];
    int sum = 0;
    #pragma unroll
    for (int i = 0; i < 16; i++) { v[i] = bh[base + i]; sum += v[i]; }
    s[t] = sum;
    __syncthreads();
    for (int off = 1; off < 1024; off <<= 1) {
        int u = (t >= off) ? s[t - off] : 0;
        __syncthreads();
        s[t] += u;
        __syncthreads();
    }
    int run = s[t] - sum;
    #pragma unroll
    for (int i = 0; i < 16; i++) { so[base + i] = run; run += v[i]; }
}

// --- partition phase 3: scatter packed (src | dlow<<16) into bucket order ---
__global__ void part_scatter(const int* __restrict__ src, const int* __restrict__ dst,
                             const int* __restrict__ so, int* __restrict__ bpack) {
    __shared__ int cur[256];
    cur[threadIdx.x] = so[threadIdx.x * PCHUNKS + blockIdx.x];
    __syncthreads();
    int base = blockIdx.x * EPC;
    for (int i = threadIdx.x; i < EPC; i += 256) {
        int s = src[base + i];
        int d = dst[base + i];
        int pos = atomicAdd(&cur[d >> 8], 1);           // LDS atomic (rank)
        bpack[pos] = s | ((d & 255) << 16);             // plain store, 16KB window
    }
}

// --- per-bucket histogram -> deg_in (no global atomics) ---
__global__ void bucket_hist(const int* __restrict__ bpack, const int* __restrict__ so,
                            int* __restrict__ deg_in) {
    __shared__ int h[256];
    h[threadIdx.x] = 0;
    __syncthreads();
    int b = blockIdx.x;
    int beg = so[b * PCHUNKS];
    int end = (b == 255) ? N_EDGES : so[(b + 1) * PCHUNKS];
    for (int i = beg + threadIdx.x; i < end; i += 256)
        atomicAdd(&h[(bpack[i] >> 16) & 255], 1);
    __syncthreads();
    deg_in[b * 256 + threadIdx.x] = h[threadIdx.x];
}

// --- 3-phase exclusive scan of deg_in -> row_start[N+1] ---
__global__ void scan1(const int* __restrict__ deg_in, int* __restrict__ partials) {
    __shared__ int red[256];
    red[threadIdx.x] = deg_in[blockIdx.x * 256 + threadIdx.x];
    __syncthreads();
    for (int off = 128; off > 0; off >>= 1) {
        if (threadIdx.x < off) red[threadIdx.x] += red[threadIdx.x + off];
        __syncthreads();
    }
    if (threadIdx.x == 0) partials[blockIdx.x] = red[0];
}
__global__ void scan2(int* __restrict__ partials) {
    __shared__ int s[256];
    int t = threadIdx.x;
    int mine = partials[t];
    s[t] = mine;
    __syncthreads();
    for (int off = 1; off < 256; off <<= 1) {
        int v = (t >= off) ? s[t - off] : 0;
        __syncthreads();
        s[t] += v;
        __syncthreads();
    }
    partials[t] = s[t] - mine;
}
__global__ void scan3(const int* __restrict__ deg_in, const int* __restrict__ partials,
                      int* __restrict__ row_start) {
    __shared__ int s[256];
    int t = threadIdx.x;
    int i = blockIdx.x * 256 + t;
    int d = deg_in[i];
    s[t] = d;
    __syncthreads();
    for (int off = 1; off < 256; off <<= 1) {
        int v = (t >= off) ? s[t - off] : 0;
        __syncthreads();
        s[t] += v;
        __syncthreads();
    }
    int val = partials[blockIdx.x] + s[t] - d;
    row_start[i] = val;
    if (i == N_NODES - 1) row_start[N_NODES] = val + d;
}

// --- deg_out phase 1: partial LDS histograms (range x chunk) ---
__global__ void oh1(const int* __restrict__ src, int* __restrict__ partial) {
    __shared__ int h[RBINS];            // 64 KB
    for (int i = threadIdx.x; i < RBINS; i += 256) h[i] = 0;
    __syncthreads();
    int chunk = blockIdx.x & (HCHUNKS - 1);
    int range = blockIdx.x / HCHUNKS;
    int rbase = range * RBINS;
    int base = chunk * EHC;
    for (int i = threadIdx.x; i < EHC; i += 256) {
        int s = src[base + i] - rbase;
        if ((unsigned)s < (unsigned)RBINS) atomicAdd(&h[s], 1);
    }
    __syncthreads();
    for (int i = threadIdx.x; i < RBINS; i += 256)
        partial[chunk * N_NODES + rbase + i] = h[i];
}
// --- deg_out phase 2: dense reduce over chunks ---
__global__ void oh2(const int* __restrict__ partial, int* __restrict__ deg_out) {
    int n = blockIdx.x * 256 + threadIdx.x;
    int s = 0;
    #pragma unroll
    for (int c = 0; c < HCHUNKS; c++) s += partial[c * N_NODES + n];
    deg_out[n] = s;
}

// --- rsqrt(clip(deg,1)) for both deg arrays ---
__global__ void rsqrt_kernel(const int* __restrict__ deg, float* __restrict__ rs) {
    int i = blockIdx.x * blockDim.x + threadIdx.x;
    if (i < 2 * N_NODES) {
        int d = deg[i];
        rs[i] = rsqrtf(d < 1 ? 1.0f : (float)d);
    }
}

// --- per-bucket CSR emit: LDS cursors seeded from row_start ---
__global__ void bucket_csr(const int* __restrict__ bpack, const int* __restrict__ so,
                           const int* __restrict__ row_start, int* __restrict__ csr_src) {
    __shared__ int cur[256];
    int b = blockIdx.x;
    cur[threadIdx.x] = row_start[b * 256 + threadIdx.x];
    __syncthreads();
    int beg = so[b * PCHUNKS];
    int end = (b == 255) ? N_EDGES : so[(b + 1) * PCHUNKS];
    for (int i = beg + threadIdx.x; i < end; i += 256) {
        int p = bpack[i];
        int pos = atomicAdd(&cur[(p >> 16) & 255], 1);  // LDS atomic
        csr_src[pos] = p & 0xFFFF;                      // store in 16KB window
    }
}

// --- prescale: xs[n] = x[n] * rs_out[n] ---
__global__ void prescale_kernel(const float4* __restrict__ x4, const float* __restrict__ rs_out,
                                float4* __restrict__ xs4) {
    int i = blockIdx.x * blockDim.x + threadIdx.x;
    int node = i >> 4;
    float r = rs_out[node];
    float4 v = x4[i];
    v.x *= r; v.y *= r; v.z *= r; v.w *= r;
    xs4[i] = v;
}

// --- fused layer: 4 nodes per wave, 16 lanes per node, float4 per lane ---
template<bool SCALE_OUT>
__global__ void fused_layer(const float4* __restrict__ xs4, const int* __restrict__ row_start,
                            const int* __restrict__ csr_src, const float* __restrict__ rs_out,
                            const float* __restrict__ rs_in, const float* __restrict__ W,
                            const float* __restrict__ b, float4* __restrict__ out4) {
    __shared__ float4 Ws4[DIM * 16];
    __shared__ float4 bs4[16];
    {
        const float4* Wg = (const float4*)W;
        for (int i = threadIdx.x; i < DIM * 16; i += blockDim.x) Ws4[i] = Wg[i];
        if (threadIdx.x < 16) bs4[threadIdx.x] = ((const float4*)b)[threadIdx.x];
    }
    __syncthreads();

    int wave_id = threadIdx.x >> 6;
    int lane = threadIdx.x & 63;
    int g = lane >> 4;
    int l = lane & 15;
    int node = blockIdx.x * 16 + wave_id * 4 + g;

    int beg = row_start[node];
    int end = row_start[node + 1];

    float4 acc = make_float4(0.f, 0.f, 0.f, 0.f);
    int k = beg;
    for (; k + UNROLL <= end; k += UNROLL) {
        int s[UNROLL];
        #pragma unroll
        for (int j = 0; j < UNROLL; j++) s[j] = csr_src[k + j];
        float4 v[UNROLL];
        #pragma unroll
        for (int j = 0; j < UNROLL; j++) v[j] = xs4[s[j] * 16 + l];
        #pragma unroll
        for (int j = 0; j < UNROLL; j++) {
            acc.x += v[j].x; acc.y += v[j].y; acc.z += v[j].z; acc.w += v[j].w;
        }
    }
    for (; k < end; k++) {
        float4 v = xs4[csr_src[k] * 16 + l];
        acc.x += v.x; acc.y += v.y; acc.z += v.z; acc.w += v.w;
    }
    float ri = rs_in[node];
    acc.x *= ri; acc.y *= ri; acc.z *= ri; acc.w *= ri;

    float4 o = bs4[l];
    int gbase = g << 4;
    #pragma unroll
    for (int m = 0; m < 16; m++) {
        float ax = __shfl(acc.x, gbase + m, 64);
        float ay = __shfl(acc.y, gbase + m, 64);
        float az = __shfl(acc.z, gbase + m, 64);
        float aw = __shfl(acc.w, gbase + m, 64);
        float4 w0 = Ws4[(4 * m + 0) * 16 + l];
        float4 w1 = Ws4[(4 * m + 1) * 16 + l];
        float4 w2 = Ws4[(4 * m + 2) * 16 + l];
        float4 w3 = Ws4[(4 * m + 3) * 16 + l];
        o.x += ax * w0.x + ay * w1.x + az * w2.x + aw * w3.x;
        o.y += ax * w0.y + ay * w1.y + az * w2.y + aw * w3.y;
        o.z += ax * w0.z + ay * w1.z + az * w2.z + aw * w3.z;
        o.w += ax * w0.w + ay * w1.w + az * w2.w + aw * w3.w;
    }
    if (SCALE_OUT) {
        float ro = rs_out[node];
        o.x = (o.x < 0.f ? 0.f : o.x) * ro;
        o.y = (o.y < 0.f ? 0.f : o.y) * ro;
        o.z = (o.z < 0.f ? 0.f : o.z) * ro;
        o.w = (o.w < 0.f ? 0.f : o.w) * ro;
    }
    out4[node * 16 + l] = o;
}

extern "C" void kernel_launch(void* const* d_in, const int* in_sizes, int n_in,
                              void* d_out, int out_size, void* d_ws, size_t ws_size,
                              hipStream_t stream) {
    const float* x   = (const float*)d_in[0];
    const int*   ei  = (const int*)d_in[1];
    const int*   src = ei;
    const int*   dst = ei + N_EDGES;
    const float* W1 = (const float*)d_in[3];
    const float* b1 = (const float*)d_in[4];
    const float* W2 = (const float*)d_in[5];
    const float* b2 = (const float*)d_in[6];
    const float* W3 = (const float*)d_in[7];
    const float* b3 = (const float*)d_in[8];
    float* out = (float*)d_out;

    // workspace layout
    char* ws = (char*)d_ws;
    int*   deg_i      = (int*)ws;                                  // [2N] out|in
    int*   deg_out_i  = deg_i;
    int*   deg_in_i   = deg_i + N_NODES;
    float* rs         = (float*)(deg_i + 2 * N_NODES);             // [2N] out|in
    float* rs_out     = rs;
    float* rs_in      = rs + N_NODES;
    int*   row_start  = (int*)(rs + 2 * N_NODES);                  // [N+1]
    int*   spartials  = row_start + (N_NODES + 1);                 // [256]
    int*   block_h    = spartials + 256;                           // [256*64]
    int*   scan_out   = block_h + 256 * PCHUNKS;                   // [256*64]
    int*   csr_src    = scan_out + 256 * PCHUNKS;                  // [E]
    float* bufA       = (float*)(csr_src + N_EDGES);               // [N*64]
    float* bufB       = bufA + (size_t)N_NODES * DIM;              // [N*64]
    int*   partial    = (int*)bufA;   // alias: dead before prescale writes bufA
    int*   bpack      = (int*)bufB;   // alias: dead before layer1 writes bufB

    const int fb = N_NODES / 16;      // 4096 blocks for fused layers

    // CSR build (counting sort by dst>>8, no scattered global atomics)
    part_hist   <<<PCHUNKS, 256, 0, stream>>>(dst, block_h);
    part_scan   <<<1, 1024, 0, stream>>>(block_h, scan_out);
    part_scatter<<<PCHUNKS, 256, 0, stream>>>(src, dst, scan_out, bpack);
    bucket_hist <<<256, 256, 0, stream>>>(bpack, scan_out, deg_in_i);
    scan1<<<256, 256, 0, stream>>>(deg_in_i, spartials);
    scan2<<<1, 256, 0, stream>>>(spartials);
    scan3<<<256, 256, 0, stream>>>(deg_in_i, spartials, row_start);

    // deg_out via partial LDS histograms
    oh1<<<RANGES * HCHUNKS, 256, 0, stream>>>(src, partial);
    oh2<<<N_NODES / 256, 256, 0, stream>>>(partial, deg_out_i);

    rsqrt_kernel<<<(2 * N_NODES) / 256, 256, 0, stream>>>(deg_i, rs);
    bucket_csr  <<<256, 256, 0, stream>>>(bpack, scan_out, row_start, csr_src);

    // prescale layer-1 input: bufA = x * rs_out
    prescale_kernel<<<(N_NODES * 16) / 256, 256, 0, stream>>>((const float4*)x, rs_out, (float4*)bufA);

    // layers: bufA -> bufB(scaled) -> bufA(scaled) -> d_out (unscaled, no relu)
    fused_layer<true ><<<fb, 256, 0, stream>>>((const float4*)bufA, row_start, csr_src, rs_out, rs_in, W1, b1, (float4*)bufB);
    fused_layer<true ><<<fb, 256, 0, stream>>>((const float4*)bufB, row_start, csr_src, rs_out, rs_in, W2, b2, (float4*)bufA);
    fused_layer<false><<<fb, 256, 0, stream>>>((const float4*)bufA, row_start, csr_src, rs_out, rs_in, W3, b3, (float4*)out);
}

// Round 6
// 322.439 us; speedup vs baseline: 3.4298x; 1.2758x over previous
//
#include <hip/hip_runtime.h>

// GraphEncoder: 3x GraphConv(norm='both'), DIM=64, fixed graph.
// R6: prep slimmed.
//  - deg_out: packed 16-bit 32K-node LDS histograms (2 ranges x 128 chunks,
//    256 blocks, 64KB LDS each) + dense reduce emitting rs_out (rsqrt fused).
//  - row_start: bucket-level prefix already in scan_out (scan_out[b*64]); the
//    per-bucket histogram kernel scans its 256 bins in LDS and emits
//    row_start + rs_in directly. scan1/2/3 + rsqrt kernels deleted.
//  Layers unchanged from R4 (4 nodes/wave, float4/lane, unroll 8).

#define N_NODES 65536
#define N_EDGES 1048576
#define DIM 64
#define UNROLL 8

#define PCHUNKS 64
#define EPC (N_EDGES / PCHUNKS)       // 16384 edges per partition chunk

#define OH_RANGES 2
#define OH_CHUNKS 128
#define OH_EPC (N_EDGES / OH_CHUNKS)  // 8192 edges per hist chunk
#define OH_WORDS 16384                // 32768 nodes packed 2-per-word (64KB)

// --- partition phase 1: per-(bucket,chunk) histogram of dst>>8 ---
__global__ void part_hist(const int* __restrict__ dst, int* __restrict__ block_hist) {
    __shared__ int h[256];
    h[threadIdx.x] = 0;
    __syncthreads();
    int base = blockIdx.x * EPC;
    for (int i = threadIdx.x; i < EPC; i += 256)
        atomicAdd(&h[dst[base + i] >> 8], 1);
    __syncthreads();
    block_hist[threadIdx.x * PCHUNKS + blockIdx.x] = h[threadIdx.x];  // [bucket][chunk]
}

// --- partition phase 2: exclusive scan of 16384 (bucket-major) ---
__global__ void part_scan(const int* __restrict__ bh, int* __restrict__ so) {
    __shared__ int s[1024];
    int t = threadIdx.x;
    int base = t * 16;
    int v[16];
    int sum = 0;
    #pragma unroll
    for (int i = 0; i < 16; i++) { v[i] = bh[base + i]; sum += v[i]; }
    s[t] = sum;
    __syncthreads();
    for (int off = 1; off < 1024; off <<= 1) {
        int u = (t >= off) ? s[t - off] : 0;
        __syncthreads();
        s[t] += u;
        __syncthreads();
    }
    int run = s[t] - sum;
    #pragma unroll
    for (int i = 0; i < 16; i++) { so[base + i] = run; run += v[i]; }
}

// --- partition phase 3: scatter packed (src | dlow<<16) into bucket order ---
__global__ void part_scatter(const int* __restrict__ src, const int* __restrict__ dst,
                             const int* __restrict__ so, int* __restrict__ bpack) {
    __shared__ int cur[256];
    cur[threadIdx.x] = so[threadIdx.x * PCHUNKS + blockIdx.x];
    __syncthreads();
    int base = blockIdx.x * EPC;
    for (int i = threadIdx.x; i < EPC; i += 256) {
        int s = src[base + i];
        int d = dst[base + i];
        int pos = atomicAdd(&cur[d >> 8], 1);           // LDS atomic (rank)
        bpack[pos] = s | ((d & 255) << 16);             // plain store, 16KB window
    }
}

// --- per-bucket histogram + LDS scan -> row_start, rs_in (scans/rsqrt fused) ---
__global__ void bucket_hist_scan(const int* __restrict__ bpack, const int* __restrict__ so,
                                 int* __restrict__ row_start, float* __restrict__ rs_in) {
    __shared__ int h[256];
    __shared__ int s[256];
    int b = blockIdx.x;
    int t = threadIdx.x;
    h[t] = 0;
    __syncthreads();
    int beg = so[b * PCHUNKS];                          // == edges before bucket b
    int end = (b == 255) ? N_EDGES : so[(b + 1) * PCHUNKS];
    for (int i = beg + t; i < end; i += 256)
        atomicAdd(&h[(bpack[i] >> 16) & 255], 1);
    __syncthreads();
    int d = h[t];
    s[t] = d;
    __syncthreads();
    for (int off = 1; off < 256; off <<= 1) {
        int v = (t >= off) ? s[t - off] : 0;
        __syncthreads();
        s[t] += v;
        __syncthreads();
    }
    int node = b * 256 + t;
    row_start[node] = beg + s[t] - d;                   // bucket base + intra-bucket excl
    rs_in[node] = rsqrtf(d < 1 ? 1.0f : (float)d);
    if (node == N_NODES - 1) row_start[N_NODES] = N_EDGES;
}

// --- deg_out phase 1: packed 16-bit 32K-node histograms ---
__global__ void oh1p(const int* __restrict__ src, unsigned* __restrict__ partial) {
    __shared__ unsigned h[OH_WORDS];                    // 64 KB
    for (int i = threadIdx.x; i < OH_WORDS; i += 256) h[i] = 0;
    __syncthreads();
    int range = blockIdx.x >> 7;                        // 0..1
    int chunk = blockIdx.x & (OH_CHUNKS - 1);
    int rbase = range << 15;                            // range * 32768
    int base = chunk * OH_EPC;
    for (int i = threadIdx.x; i < OH_EPC; i += 256) {
        int v = src[base + i] - rbase;
        if ((unsigned)v < 32768u)
            atomicAdd(&h[v >> 1], 1u << ((v & 1) * 16));
    }
    __syncthreads();
    unsigned* dp = partial + (size_t)blockIdx.x * OH_WORDS;
    for (int i = threadIdx.x; i < OH_WORDS; i += 256) dp[i] = h[i];
}

// --- deg_out phase 2: dense reduce over chunks, emit rs_out (rsqrt fused) ---
__global__ void oh2p(const unsigned* __restrict__ partial, float2* __restrict__ rs_out2) {
    int t = blockIdx.x * 256 + threadIdx.x;             // 0..32767 (range,word)
    int range = t >> 14;
    int w = t & (OH_WORDS - 1);
    const unsigned* p = partial + (size_t)range * OH_CHUNKS * OH_WORDS + w;
    int lo = 0, hi = 0;
    for (int c = 0; c < OH_CHUNKS; c++) {
        unsigned v = p[(size_t)c * OH_WORDS];
        lo += (int)(v & 0xFFFFu);
        hi += (int)(v >> 16);
    }
    int pair = (range << 14) + w;                       // node pair index
    rs_out2[pair] = make_float2(rsqrtf(lo < 1 ? 1.0f : (float)lo),
                                rsqrtf(hi < 1 ? 1.0f : (float)hi));
}

// --- per-bucket CSR emit: LDS cursors seeded from row_start ---
__global__ void bucket_csr(const int* __restrict__ bpack, const int* __restrict__ so,
                           const int* __restrict__ row_start, int* __restrict__ csr_src) {
    __shared__ int cur[256];
    int b = blockIdx.x;
    cur[threadIdx.x] = row_start[b * 256 + threadIdx.x];
    __syncthreads();
    int beg = so[b * PCHUNKS];
    int end = (b == 255) ? N_EDGES : so[(b + 1) * PCHUNKS];
    for (int i = beg + threadIdx.x; i < end; i += 256) {
        int p = bpack[i];
        int pos = atomicAdd(&cur[(p >> 16) & 255], 1);  // LDS atomic
        csr_src[pos] = p & 0xFFFF;                      // store in 16KB window
    }
}

// --- prescale: xs[n] = x[n] * rs_out[n] ---
__global__ void prescale_kernel(const float4* __restrict__ x4, const float* __restrict__ rs_out,
                                float4* __restrict__ xs4) {
    int i = blockIdx.x * blockDim.x + threadIdx.x;
    int node = i >> 4;
    float r = rs_out[node];
    float4 v = x4[i];
    v.x *= r; v.y *= r; v.z *= r; v.w *= r;
    xs4[i] = v;
}

// --- fused layer: 4 nodes per wave, 16 lanes per node, float4 per lane ---
template<bool SCALE_OUT>
__global__ void fused_layer(const float4* __restrict__ xs4, const int* __restrict__ row_start,
                            const int* __restrict__ csr_src, const float* __restrict__ rs_out,
                            const float* __restrict__ rs_in, const float* __restrict__ W,
                            const float* __restrict__ b, float4* __restrict__ out4) {
    __shared__ float4 Ws4[DIM * 16];
    __shared__ float4 bs4[16];
    {
        const float4* Wg = (const float4*)W;
        for (int i = threadIdx.x; i < DIM * 16; i += blockDim.x) Ws4[i] = Wg[i];
        if (threadIdx.x < 16) bs4[threadIdx.x] = ((const float4*)b)[threadIdx.x];
    }
    __syncthreads();

    int wave_id = threadIdx.x >> 6;
    int lane = threadIdx.x & 63;
    int g = lane >> 4;
    int l = lane & 15;
    int node = blockIdx.x * 16 + wave_id * 4 + g;

    int beg = row_start[node];
    int end = row_start[node + 1];

    float4 acc = make_float4(0.f, 0.f, 0.f, 0.f);
    int k = beg;
    for (; k + UNROLL <= end; k += UNROLL) {
        int s[UNROLL];
        #pragma unroll
        for (int j = 0; j < UNROLL; j++) s[j] = csr_src[k + j];
        float4 v[UNROLL];
        #pragma unroll
        for (int j = 0; j < UNROLL; j++) v[j] = xs4[s[j] * 16 + l];
        #pragma unroll
        for (int j = 0; j < UNROLL; j++) {
            acc.x += v[j].x; acc.y += v[j].y; acc.z += v[j].z; acc.w += v[j].w;
        }
    }
    for (; k < end; k++) {
        float4 v = xs4[csr_src[k] * 16 + l];
        acc.x += v.x; acc.y += v.y; acc.z += v.z; acc.w += v.w;
    }
    float ri = rs_in[node];
    acc.x *= ri; acc.y *= ri; acc.z *= ri; acc.w *= ri;

    float4 o = bs4[l];
    int gbase = g << 4;
    #pragma unroll
    for (int m = 0; m < 16; m++) {
        float ax = __shfl(acc.x, gbase + m, 64);
        float ay = __shfl(acc.y, gbase + m, 64);
        float az = __shfl(acc.z, gbase + m, 64);
        float aw = __shfl(acc.w, gbase + m, 64);
        float4 w0 = Ws4[(4 * m + 0) * 16 + l];
        float4 w1 = Ws4[(4 * m + 1) * 16 + l];
        float4 w2 = Ws4[(4 * m + 2) * 16 + l];
        float4 w3 = Ws4[(4 * m + 3) * 16 + l];
        o.x += ax * w0.x + ay * w1.x + az * w2.x + aw * w3.x;
        o.y += ax * w0.y + ay * w1.y + az * w2.y + aw * w3.y;
        o.z += ax * w0.z + ay * w1.z + az * w2.z + aw * w3.z;
        o.w += ax * w0.w + ay * w1.w + az * w2.w + aw * w3.w;
    }
    if (SCALE_OUT) {
        float ro = rs_out[node];
        o.x = (o.x < 0.f ? 0.f : o.x) * ro;
        o.y = (o.y < 0.f ? 0.f : o.y) * ro;
        o.z = (o.z < 0.f ? 0.f : o.z) * ro;
        o.w = (o.w < 0.f ? 0.f : o.w) * ro;
    }
    out4[node * 16 + l] = o;
}

extern "C" void kernel_launch(void* const* d_in, const int* in_sizes, int n_in,
                              void* d_out, int out_size, void* d_ws, size_t ws_size,
                              hipStream_t stream) {
    const float* x   = (const float*)d_in[0];
    const int*   ei  = (const int*)d_in[1];
    const int*   src = ei;
    const int*   dst = ei + N_EDGES;
    const float* W1 = (const float*)d_in[3];
    const float* b1 = (const float*)d_in[4];
    const float* W2 = (const float*)d_in[5];
    const float* b2 = (const float*)d_in[6];
    const float* W3 = (const float*)d_in[7];
    const float* b3 = (const float*)d_in[8];
    float* out = (float*)d_out;

    // workspace layout (~37 MB):
    // rs[2N] | row_start[N+1] | block_h[16K] | scan_out[16K] | csr[E] | bufA[16M] | bufB[16M]
    // aliases: partial (16MB) over bufA (dead until prescale);
    //          bpack (4MB) over bufB (dead until layer 1 output).
    char* ws = (char*)d_ws;
    float* rs        = (float*)ws;                                 // [2N] out|in
    float* rs_out    = rs;
    float* rs_in     = rs + N_NODES;
    int*   row_start = (int*)(rs + 2 * N_NODES);                   // [N+1]
    int*   block_h   = row_start + (N_NODES + 256);                // [16384] (padded start)
    int*   scan_out  = block_h + 256 * PCHUNKS;                    // [16384]
    int*   csr_src   = scan_out + 256 * PCHUNKS;                   // [E]
    float* bufA      = (float*)(csr_src + N_EDGES);                // [N*64]
    float* bufB      = bufA + (size_t)N_NODES * DIM;               // [N*64]
    unsigned* partial = (unsigned*)bufA;                           // [256*16384] = 16MB
    int*   bpack     = (int*)bufB;                                 // [E] = 4MB

    const int fb = N_NODES / 16;      // 4096 blocks for fused layers

    // CSR build (counting sort by dst>>8; zero scattered global atomics)
    part_hist       <<<PCHUNKS, 256, 0, stream>>>(dst, block_h);
    part_scan       <<<1, 1024, 0, stream>>>(block_h, scan_out);
    part_scatter    <<<PCHUNKS, 256, 0, stream>>>(src, dst, scan_out, bpack);
    bucket_hist_scan<<<256, 256, 0, stream>>>(bpack, scan_out, row_start, rs_in);

    // deg_out -> rs_out (packed 16-bit histograms)
    oh1p<<<OH_RANGES * OH_CHUNKS, 256, 0, stream>>>(src, partial);
    oh2p<<<(OH_RANGES * OH_WORDS) / 256, 256, 0, stream>>>(partial, (float2*)rs_out);

    bucket_csr<<<256, 256, 0, stream>>>(bpack, scan_out, row_start, csr_src);

    // prescale layer-1 input: bufA = x * rs_out  (partial is dead now)
    prescale_kernel<<<(N_NODES * 16) / 256, 256, 0, stream>>>((const float4*)x, rs_out, (float4*)bufA);

    // layers: bufA -> bufB(scaled) -> bufA(scaled) -> d_out (unscaled, no relu)
    fused_layer<true ><<<fb, 256, 0, stream>>>((const float4*)bufA, row_start, csr_src, rs_out, rs_in, W1, b1, (float4*)bufB);
    fused_layer<true ><<<fb, 256, 0, stream>>>((const float4*)bufB, row_start, csr_src, rs_out, rs_in, W2, b2, (float4*)bufA);
    fused_layer<false><<<fb, 256, 0, stream>>>((const float4*)bufA, row_start, csr_src, rs_out, rs_in, W3, b3, (float4*)out);
}

// Round 7
// 316.275 us; speedup vs baseline: 3.4967x; 1.0195x over previous
//
#include <hip/hip_runtime.h>

// GraphEncoder: 3x GraphConv(norm='both'), DIM=64, fixed graph.
// R7: - layer gather loop: clamped 8-wide (no serial remainder; OOB slots hit
//       an appended zero row -> fully pipelined ceil(deg/8) iterations).
//     - csr_src stored as ushort (src < 65536): half the index traffic.
//     - prep: bucket hist+scan+csr-emit fused into one kernel; deg_out hist
//       8-bit packed (whole node range in one 64KB LDS block, 128 chunks);
//       zero rows seeded in part_hist. 10 dispatches total.

#define N_NODES 65536
#define N_EDGES 1048576
#define DIM 64

#define PCHUNKS 64
#define EPC (N_EDGES / PCHUNKS)       // 16384 edges per partition chunk

#define OH_CHUNKS 128
#define OH_EPC (N_EDGES / OH_CHUNKS)  // 8192 edges per hist chunk
#define OH_WORDS 16384                // 65536 nodes packed 4-per-word (64KB)

// --- partition phase 1: per-(bucket,chunk) histogram of dst>>8; also zero rows ---
__global__ void part_hist(const int* __restrict__ dst, int* __restrict__ block_hist,
                          float4* __restrict__ zeroA, float4* __restrict__ zeroB) {
    __shared__ int h[256];
    h[threadIdx.x] = 0;
    __syncthreads();
    if (blockIdx.x == 0) {           // seed zero rows (row N_NODES of each table)
        if (threadIdx.x < 16) zeroA[threadIdx.x] = make_float4(0.f, 0.f, 0.f, 0.f);
        else if (threadIdx.x < 32) zeroB[threadIdx.x - 16] = make_float4(0.f, 0.f, 0.f, 0.f);
    }
    int base = blockIdx.x * EPC;
    for (int i = threadIdx.x; i < EPC; i += 256)
        atomicAdd(&h[dst[base + i] >> 8], 1);
    __syncthreads();
    block_hist[threadIdx.x * PCHUNKS + blockIdx.x] = h[threadIdx.x];  // [bucket][chunk]
}

// --- partition phase 2: exclusive scan of 16384 (bucket-major) ---
__global__ void part_scan(const int* __restrict__ bh, int* __restrict__ so) {
    __shared__ int s[1024];
    int t = threadIdx.x;
    int base = t * 16;
    int v[16];
    int sum = 0;
    #pragma unroll
    for (int i = 0; i < 16; i++) { v[i] = bh[base + i]; sum += v[i]; }
    s[t] = sum;
    __syncthreads();
    for (int off = 1; off < 1024; off <<= 1) {
        int u = (t >= off) ? s[t - off] : 0;
        __syncthreads();
        s[t] += u;
        __syncthreads();
    }
    int run = s[t] - sum;
    #pragma unroll
    for (int i = 0; i < 16; i++) { so[base + i] = run; run += v[i]; }
}

// --- partition phase 3: scatter packed (src | dlow<<16) into bucket order ---
__global__ void part_scatter(const int* __restrict__ src, const int* __restrict__ dst,
                             const int* __restrict__ so, int* __restrict__ bpack) {
    __shared__ int cur[256];
    cur[threadIdx.x] = so[threadIdx.x * PCHUNKS + blockIdx.x];
    __syncthreads();
    int base = blockIdx.x * EPC;
    for (int i = threadIdx.x; i < EPC; i += 256) {
        int s = src[base + i];
        int d = dst[base + i];
        int pos = atomicAdd(&cur[d >> 8], 1);           // LDS atomic (rank)
        bpack[pos] = s | ((d & 255) << 16);             // plain store, 16KB window
    }
}

// --- per-bucket: histogram -> LDS scan -> row_start + rs_in -> csr emit (fused) ---
__global__ void bucket_fused(const int* __restrict__ bpack, const int* __restrict__ so,
                             int* __restrict__ row_start, float* __restrict__ rs_in,
                             unsigned short* __restrict__ csr_src) {
    __shared__ int h[256];
    __shared__ int s[256];
    __shared__ int cur[256];
    int b = blockIdx.x;
    int t = threadIdx.x;
    h[t] = 0;
    __syncthreads();
    int beg = so[b * PCHUNKS];
    int end = (b == 255) ? N_EDGES : so[(b + 1) * PCHUNKS];
    for (int i = beg + t; i < end; i += 256)
        atomicAdd(&h[(bpack[i] >> 16) & 255], 1);
    __syncthreads();
    int d = h[t];
    s[t] = d;
    __syncthreads();
    for (int off = 1; off < 256; off <<= 1) {
        int v = (t >= off) ? s[t - off] : 0;
        __syncthreads();
        s[t] += v;
        __syncthreads();
    }
    int rsv = beg + s[t] - d;                           // exclusive prefix
    int node = b * 256 + t;
    row_start[node] = rsv;
    rs_in[node] = rsqrtf(d < 1 ? 1.0f : (float)d);
    if (node == N_NODES - 1) row_start[N_NODES] = N_EDGES;
    cur[t] = rsv;
    __syncthreads();
    for (int i = beg + t; i < end; i += 256) {
        int p = bpack[i];
        int pos = atomicAdd(&cur[(p >> 16) & 255], 1);  // LDS atomic
        csr_src[pos] = (unsigned short)(p & 0xFFFF);    // 8KB window scatter
    }
}

// --- deg_out phase 1: 8-bit packed full-range histograms (128 chunks) ---
__global__ void oh1p(const int* __restrict__ src, unsigned* __restrict__ partial) {
    __shared__ unsigned h[OH_WORDS];                    // 64 KB, all 65536 nodes
    for (int i = threadIdx.x; i < OH_WORDS; i += 256) h[i] = 0;
    __syncthreads();
    int base = blockIdx.x * OH_EPC;
    for (int i = threadIdx.x; i < OH_EPC; i += 256) {
        int v = src[base + i];
        atomicAdd(&h[v >> 2], 1u << ((v & 3) * 8));     // max per-chunk count << 255
    }
    __syncthreads();
    unsigned* dp = partial + (size_t)blockIdx.x * OH_WORDS;
    for (int i = threadIdx.x; i < OH_WORDS; i += 256) dp[i] = h[i];
}

// --- deg_out phase 2: byte-reduce over chunks, emit rs_out (rsqrt fused) ---
__global__ void oh2p(const unsigned* __restrict__ partial, float4* __restrict__ rs_out4) {
    int w = blockIdx.x * 256 + threadIdx.x;             // word = 4 nodes
    int c0 = 0, c1 = 0, c2 = 0, c3 = 0;
    for (int c = 0; c < OH_CHUNKS; c++) {
        unsigned v = partial[(size_t)c * OH_WORDS + w];
        c0 += (int)(v & 255u);
        c1 += (int)((v >> 8) & 255u);
        c2 += (int)((v >> 16) & 255u);
        c3 += (int)(v >> 24);
    }
    rs_out4[w] = make_float4(rsqrtf(c0 < 1 ? 1.0f : (float)c0),
                             rsqrtf(c1 < 1 ? 1.0f : (float)c1),
                             rsqrtf(c2 < 1 ? 1.0f : (float)c2),
                             rsqrtf(c3 < 1 ? 1.0f : (float)c3));
}

// --- prescale: xs[n] = x[n] * rs_out[n] ---
__global__ void prescale_kernel(const float4* __restrict__ x4, const float* __restrict__ rs_out,
                                float4* __restrict__ xs4) {
    int i = blockIdx.x * blockDim.x + threadIdx.x;
    int node = i >> 4;
    float r = rs_out[node];
    float4 v = x4[i];
    v.x *= r; v.y *= r; v.z *= r; v.w *= r;
    xs4[i] = v;
}

// --- fused layer: 4 nodes/wave, 16 lanes/node, float4/lane, clamped 8-wide ---
template<bool SCALE_OUT>
__global__ void fused_layer(const float4* __restrict__ xs4, const int* __restrict__ row_start,
                            const unsigned short* __restrict__ csr_src,
                            const float* __restrict__ rs_out, const float* __restrict__ rs_in,
                            const float* __restrict__ W, const float* __restrict__ b,
                            float4* __restrict__ out4) {
    __shared__ float4 Ws4[DIM * 16];
    __shared__ float4 bs4[16];
    {
        const float4* Wg = (const float4*)W;
        for (int i = threadIdx.x; i < DIM * 16; i += blockDim.x) Ws4[i] = Wg[i];
        if (threadIdx.x < 16) bs4[threadIdx.x] = ((const float4*)b)[threadIdx.x];
    }
    __syncthreads();

    int wave_id = threadIdx.x >> 6;
    int lane = threadIdx.x & 63;
    int g = lane >> 4;
    int l = lane & 15;
    int node = blockIdx.x * 16 + wave_id * 4 + g;

    int beg = row_start[node];
    int end = row_start[node + 1];

    float4 acc = make_float4(0.f, 0.f, 0.f, 0.f);
    for (int k = beg; k < end; k += 8) {
        int s[8];
        #pragma unroll
        for (int j = 0; j < 8; j++) {
            int kk = k + j;
            int idx = csr_src[kk];                      // csr padded by 8 -> safe
            s[j] = (kk < end) ? idx : N_NODES;          // OOB -> zero row (L1-hot)
        }
        float4 v[8];
        #pragma unroll
        for (int j = 0; j < 8; j++) v[j] = xs4[s[j] * 16 + l];
        #pragma unroll
        for (int j = 0; j < 8; j++) {
            acc.x += v[j].x; acc.y += v[j].y; acc.z += v[j].z; acc.w += v[j].w;
        }
    }
    float ri = rs_in[node];
    acc.x *= ri; acc.y *= ri; acc.z *= ri; acc.w *= ri;

    float4 o = bs4[l];
    int gbase = g << 4;
    #pragma unroll
    for (int m = 0; m < 16; m++) {
        float ax = __shfl(acc.x, gbase + m, 64);
        float ay = __shfl(acc.y, gbase + m, 64);
        float az = __shfl(acc.z, gbase + m, 64);
        float aw = __shfl(acc.w, gbase + m, 64);
        float4 w0 = Ws4[(4 * m + 0) * 16 + l];
        float4 w1 = Ws4[(4 * m + 1) * 16 + l];
        float4 w2 = Ws4[(4 * m + 2) * 16 + l];
        float4 w3 = Ws4[(4 * m + 3) * 16 + l];
        o.x += ax * w0.x + ay * w1.x + az * w2.x + aw * w3.x;
        o.y += ax * w0.y + ay * w1.y + az * w2.y + aw * w3.y;
        o.z += ax * w0.z + ay * w1.z + az * w2.z + aw * w3.z;
        o.w += ax * w0.w + ay * w1.w + az * w2.w + aw * w3.w;
    }
    if (SCALE_OUT) {
        float ro = rs_out[node];
        o.x = (o.x < 0.f ? 0.f : o.x) * ro;
        o.y = (o.y < 0.f ? 0.f : o.y) * ro;
        o.z = (o.z < 0.f ? 0.f : o.z) * ro;
        o.w = (o.w < 0.f ? 0.f : o.w) * ro;
    }
    out4[node * 16 + l] = o;
}

extern "C" void kernel_launch(void* const* d_in, const int* in_sizes, int n_in,
                              void* d_out, int out_size, void* d_ws, size_t ws_size,
                              hipStream_t stream) {
    const float* x   = (const float*)d_in[0];
    const int*   ei  = (const int*)d_in[1];
    const int*   src = ei;
    const int*   dst = ei + N_EDGES;
    const float* W1 = (const float*)d_in[3];
    const float* b1 = (const float*)d_in[4];
    const float* W2 = (const float*)d_in[5];
    const float* b2 = (const float*)d_in[6];
    const float* W3 = (const float*)d_in[7];
    const float* b3 = (const float*)d_in[8];
    float* out = (float*)d_out;

    // workspace (~36.6 MB):
    // rs[2N] f32 | row_start[N+256] | block_h[16K] | scan_out[16K] |
    // csr[E+8] u16 | bufA[(N+1)*64] f32 | bufB[(N+1)*64] f32
    // aliases: partial (8MB) over bufA head (dead before prescale);
    //          bpack (4MB) over bufB head (dead before layer-1 output).
    //          zero rows live at row N_NODES (offset 16MB) -> no alias overlap.
    char* ws = (char*)d_ws;
    float* rs        = (float*)ws;                                 // [2N]
    float* rs_out    = rs;
    float* rs_in     = rs + N_NODES;
    int*   row_start = (int*)(rs + 2 * N_NODES);                   // [N+256]
    int*   block_h   = row_start + (N_NODES + 256);                // [16384]
    int*   scan_out  = block_h + 256 * PCHUNKS;                    // [16384]
    unsigned short* csr_src = (unsigned short*)(scan_out + 256 * PCHUNKS); // [E+8]
    float* bufA      = (float*)(csr_src + N_EDGES + 8);            // [(N+1)*64]
    float* bufB      = bufA + (size_t)(N_NODES + 1) * DIM;         // [(N+1)*64]
    unsigned* partial = (unsigned*)bufA;                           // [128*16384] = 8MB
    int*   bpack     = (int*)bufB;                                 // [E] = 4MB
    float4* zeroA    = (float4*)(bufA + (size_t)N_NODES * DIM);    // row N_NODES
    float4* zeroB    = (float4*)(bufB + (size_t)N_NODES * DIM);

    const int fb = N_NODES / 16;      // 4096 blocks for fused layers

    // CSR build (counting sort by dst>>8; zero scattered global atomics)
    part_hist   <<<PCHUNKS, 256, 0, stream>>>(dst, block_h, zeroA, zeroB);
    part_scan   <<<1, 1024, 0, stream>>>(block_h, scan_out);
    part_scatter<<<PCHUNKS, 256, 0, stream>>>(src, dst, scan_out, bpack);
    bucket_fused<<<256, 256, 0, stream>>>(bpack, scan_out, row_start, rs_in, csr_src);

    // deg_out -> rs_out (8-bit packed histograms)
    oh1p<<<OH_CHUNKS, 256, 0, stream>>>(src, partial);
    oh2p<<<OH_WORDS / 256, 256, 0, stream>>>(partial, (float4*)rs_out);

    // prescale layer-1 input: bufA = x * rs_out (partial dead from here)
    prescale_kernel<<<(N_NODES * 16) / 256, 256, 0, stream>>>((const float4*)x, rs_out, (float4*)bufA);

    // layers: bufA -> bufB(scaled) -> bufA(scaled) -> d_out (unscaled, no relu)
    fused_layer<true ><<<fb, 256, 0, stream>>>((const float4*)bufA, row_start, csr_src, rs_out, rs_in, W1, b1, (float4*)bufB);
    fused_layer<true ><<<fb, 256, 0, stream>>>((const float4*)bufB, row_start, csr_src, rs_out, rs_in, W2, b2, (float4*)bufA);
    fused_layer<false><<<fb, 256, 0, stream>>>((const float4*)bufA, row_start, csr_src, rs_out, rs_in, W3, b3, (float4*)out);
}

// Round 8
// 299.583 us; speedup vs baseline: 3.6915x; 1.0557x over previous
//
#include <hip/hip_runtime.h>

// GraphEncoder: 3x GraphConv(norm='both'), DIM=64, fixed graph.
// R8: prep collapsed to 5 kernels, 8 dispatches total, 0 memsets.
//  - edge_hist: ONE pass over edges -> partition hist (dst, 256x256) + 8-bit
//    packed src histogram (64KB LDS) + zero-row seeding.
//  - part_scan: 64K-entry scan (int4) -> 256 scatter chunks (4x parallelism).
//  - bucket_fused: bucket staged in LDS (single bpack read) -> hist/scan/emit.
//  - oh2p_prescale: partial-reduce -> rs_out fused with xs = x*rs_out.
//  - layer: clamped 16-wide gather (1 iter for ~57% of nodes; OOB slots hit
//    L1-hot zero row). 4 nodes/wave, 16 lanes/node, float4/lane.

#define N_NODES 65536
#define N_EDGES 1048576
#define DIM 64

#define CHUNKS 256
#define EPC (N_EDGES / CHUNKS)        // 4096 edges per scatter chunk
#define HB 128                        // edge_hist blocks (2 chunks each)
#define OH_WORDS 16384                // 65536 nodes packed 4-per-word (64KB)

// --- one pass over edges: dst partition hist + packed src hist + zero rows ---
__global__ void edge_hist(const int* __restrict__ src, const int* __restrict__ dst,
                          int* __restrict__ block_hist, unsigned* __restrict__ partial,
                          float4* __restrict__ zeroA, float4* __restrict__ zeroB) {
    __shared__ unsigned h[OH_WORDS];  // 64 KB: src histogram, 8-bit x4 packed
    __shared__ int bh[2][256];        // dst bucket hist for the block's 2 chunks
    int t = threadIdx.x;
    int j = blockIdx.x;               // 0..127
    for (int i = t; i < OH_WORDS; i += 256) h[i] = 0;
    bh[0][t] = 0; bh[1][t] = 0;
    __syncthreads();
    if (j == 0) {                     // seed zero rows (row N_NODES of both tables)
        if (t < 16) zeroA[t] = make_float4(0.f, 0.f, 0.f, 0.f);
        else if (t < 32) zeroB[t - 16] = make_float4(0.f, 0.f, 0.f, 0.f);
    }
    int base = j * (2 * EPC);
    for (int i = t; i < 2 * EPC; i += 256) {
        int s = src[base + i];
        int d = dst[base + i];
        atomicAdd(&h[s >> 2], 1u << ((s & 3) * 8));   // per-chunk count << 255
        atomicAdd(&bh[i >> 12][d >> 8], 1);           // i<4096 -> chunk 2j, else 2j+1
    }
    __syncthreads();
    unsigned* dp = partial + (size_t)j * OH_WORDS;
    for (int i = t; i < OH_WORDS; i += 256) dp[i] = h[i];
    block_hist[t * CHUNKS + 2 * j]     = bh[0][t];    // [bucket][chunk]
    block_hist[t * CHUNKS + 2 * j + 1] = bh[1][t];
}

// --- exclusive scan of 65536 (bucket-major [bucket][chunk]) ---
__global__ void part_scan(const int* __restrict__ bh, int* __restrict__ so) {
    __shared__ int s[1024];
    int t = threadIdx.x;
    const int4* b4 = (const int4*)(bh + t * 64);
    int4 v[16];
    int sum = 0;
    #pragma unroll
    for (int i = 0; i < 16; i++) {
        v[i] = b4[i];
        sum += v[i].x + v[i].y + v[i].z + v[i].w;
    }
    s[t] = sum;
    __syncthreads();
    for (int off = 1; off < 1024; off <<= 1) {
        int u = (t >= off) ? s[t - off] : 0;
        __syncthreads();
        s[t] += u;
        __syncthreads();
    }
    int run = s[t] - sum;
    int* o = so + t * 64;
    #pragma unroll
    for (int i = 0; i < 16; i++) {
        o[4 * i + 0] = run; run += v[i].x;
        o[4 * i + 1] = run; run += v[i].y;
        o[4 * i + 2] = run; run += v[i].z;
        o[4 * i + 3] = run; run += v[i].w;
    }
}

// --- scatter packed (src | dlow<<16) into bucket order, 256 chunks ---
__global__ void part_scatter(const int* __restrict__ src, const int* __restrict__ dst,
                             const int* __restrict__ so, int* __restrict__ bpack) {
    __shared__ int cur[256];
    cur[threadIdx.x] = so[threadIdx.x * CHUNKS + blockIdx.x];
    __syncthreads();
    int base = blockIdx.x * EPC;
    for (int i = threadIdx.x; i < EPC; i += 256) {
        int s = src[base + i];
        int d = dst[base + i];
        int pos = atomicAdd(&cur[d >> 8], 1);          // LDS atomic (rank)
        bpack[pos] = s | ((d & 255) << 16);
    }
}

// --- per-bucket (LDS-staged): hist -> scan -> row_start+rs_in -> csr emit ---
__global__ void bucket_fused(const int* __restrict__ bpack, const int* __restrict__ so,
                             int* __restrict__ row_start, float* __restrict__ rs_in,
                             unsigned short* __restrict__ csr_src) {
    __shared__ int stage[8192];                        // 32 KB (bucket mean 4096)
    __shared__ int h[256], sc[256], cur[256];
    int b = blockIdx.x;
    int t = threadIdx.x;
    int beg = so[b * CHUNKS];
    int end = (b == 255) ? N_EDGES : so[(b + 1) * CHUNKS];
    int n = end - beg;
    h[t] = 0;
    __syncthreads();
    for (int i = t; i < n; i += 256) {
        int p = bpack[beg + i];
        if (i < 8192) stage[i] = p;                    // overflow guard (never hit)
        atomicAdd(&h[(p >> 16) & 255], 1);
    }
    __syncthreads();
    int d = h[t];
    sc[t] = d;
    __syncthreads();
    for (int off = 1; off < 256; off <<= 1) {
        int v = (t >= off) ? sc[t - off] : 0;
        __syncthreads();
        sc[t] += v;
        __syncthreads();
    }
    int rsv = beg + sc[t] - d;                         // exclusive prefix
    int node = b * 256 + t;
    row_start[node] = rsv;
    rs_in[node] = rsqrtf(d < 1 ? 1.0f : (float)d);
    if (node == N_NODES - 1) row_start[N_NODES] = N_EDGES;
    cur[t] = rsv;
    __syncthreads();
    for (int i = t; i < n; i += 256) {
        int p = (i < 8192) ? stage[i] : bpack[beg + i];
        int pos = atomicAdd(&cur[(p >> 16) & 255], 1); // LDS atomic
        csr_src[pos] = (unsigned short)(p & 0xFFFF);   // 8KB window scatter
    }
}

// --- reduce src histograms -> rs_out, fused with prescale xs = x*rs_out ---
__global__ void oh2p_prescale(const unsigned* __restrict__ partial,
                              float* __restrict__ rs_out,
                              const float4* __restrict__ x4, float4* __restrict__ xs4) {
    __shared__ float rsl[256];
    int b = blockIdx.x;
    int t = threadIdx.x;
    if (t < 64) {
        int w = b * 64 + t;                            // word = 4 nodes
        int c0 = 0, c1 = 0, c2 = 0, c3 = 0;
        for (int c = 0; c < HB; c++) {
            unsigned v = partial[(size_t)c * OH_WORDS + w];
            c0 += (int)(v & 255u);
            c1 += (int)((v >> 8) & 255u);
            c2 += (int)((v >> 16) & 255u);
            c3 += (int)(v >> 24);
        }
        float4 r = make_float4(rsqrtf(c0 < 1 ? 1.0f : (float)c0),
                               rsqrtf(c1 < 1 ? 1.0f : (float)c1),
                               rsqrtf(c2 < 1 ? 1.0f : (float)c2),
                               rsqrtf(c3 < 1 ? 1.0f : (float)c3));
        ((float4*)rs_out)[w] = r;
        rsl[t * 4 + 0] = r.x; rsl[t * 4 + 1] = r.y;
        rsl[t * 4 + 2] = r.z; rsl[t * 4 + 3] = r.w;
    }
    __syncthreads();
    int rowbase = b * 256 * 16;                        // float4 units
    for (int i = t; i < 4096; i += 256) {
        float r = rsl[i >> 4];
        float4 v = x4[rowbase + i];
        v.x *= r; v.y *= r; v.z *= r; v.w *= r;
        xs4[rowbase + i] = v;
    }
}

// --- fused layer: 4 nodes/wave, 16 lanes/node, float4/lane, clamped 16-wide ---
template<bool SCALE_OUT>
__global__ void fused_layer(const float4* __restrict__ xs4, const int* __restrict__ row_start,
                            const unsigned short* __restrict__ csr_src,
                            const float* __restrict__ rs_out, const float* __restrict__ rs_in,
                            const float* __restrict__ W, const float* __restrict__ b,
                            float4* __restrict__ out4) {
    __shared__ float4 Ws4[DIM * 16];
    __shared__ float4 bs4[16];
    {
        const float4* Wg = (const float4*)W;
        for (int i = threadIdx.x; i < DIM * 16; i += blockDim.x) Ws4[i] = Wg[i];
        if (threadIdx.x < 16) bs4[threadIdx.x] = ((const float4*)b)[threadIdx.x];
    }
    __syncthreads();

    int wave_id = threadIdx.x >> 6;
    int lane = threadIdx.x & 63;
    int g = lane >> 4;
    int l = lane & 15;
    int node = blockIdx.x * 16 + wave_id * 4 + g;

    int beg = row_start[node];
    int end = row_start[node + 1];

    float4 acc = make_float4(0.f, 0.f, 0.f, 0.f);
    for (int k = beg; k < end; k += 16) {
        int s[16];
        #pragma unroll
        for (int j = 0; j < 16; j++) {
            int kk = k + j;
            int idx = csr_src[kk];                     // csr padded by 16 -> safe
            s[j] = (kk < end) ? idx : N_NODES;         // OOB -> zero row (L1-hot)
        }
        float4 v[16];
        #pragma unroll
        for (int j = 0; j < 16; j++) v[j] = xs4[s[j] * 16 + l];
        #pragma unroll
        for (int j = 0; j < 16; j++) {
            acc.x += v[j].x; acc.y += v[j].y; acc.z += v[j].z; acc.w += v[j].w;
        }
    }
    float ri = rs_in[node];
    acc.x *= ri; acc.y *= ri; acc.z *= ri; acc.w *= ri;

    float4 o = bs4[l];
    int gbase = g << 4;
    #pragma unroll
    for (int m = 0; m < 16; m++) {
        float ax = __shfl(acc.x, gbase + m, 64);
        float ay = __shfl(acc.y, gbase + m, 64);
        float az = __shfl(acc.z, gbase + m, 64);
        float aw = __shfl(acc.w, gbase + m, 64);
        float4 w0 = Ws4[(4 * m + 0) * 16 + l];
        float4 w1 = Ws4[(4 * m + 1) * 16 + l];
        float4 w2 = Ws4[(4 * m + 2) * 16 + l];
        float4 w3 = Ws4[(4 * m + 3) * 16 + l];
        o.x += ax * w0.x + ay * w1.x + az * w2.x + aw * w3.x;
        o.y += ax * w0.y + ay * w1.y + az * w2.y + aw * w3.y;
        o.z += ax * w0.z + ay * w1.z + az * w2.z + aw * w3.z;
        o.w += ax * w0.w + ay * w1.w + az * w2.w + aw * w3.w;
    }
    if (SCALE_OUT) {
        float ro = rs_out[node];
        o.x = (o.x < 0.f ? 0.f : o.x) * ro;
        o.y = (o.y < 0.f ? 0.f : o.y) * ro;
        o.z = (o.z < 0.f ? 0.f : o.z) * ro;
        o.w = (o.w < 0.f ? 0.f : o.w) * ro;
    }
    out4[node * 16 + l] = o;
}

extern "C" void kernel_launch(void* const* d_in, const int* in_sizes, int n_in,
                              void* d_out, int out_size, void* d_ws, size_t ws_size,
                              hipStream_t stream) {
    const float* x   = (const float*)d_in[0];
    const int*   ei  = (const int*)d_in[1];
    const int*   src = ei;
    const int*   dst = ei + N_EDGES;
    const float* W1 = (const float*)d_in[3];
    const float* b1 = (const float*)d_in[4];
    const float* W2 = (const float*)d_in[5];
    const float* b2 = (const float*)d_in[6];
    const float* W3 = (const float*)d_in[7];
    const float* b3 = (const float*)d_in[8];
    float* out = (float*)d_out;

    // workspace:
    // rs[2N] f32 | row_start[N+256] | block_hist[64K] | so[64K] | csr[E+16] u16 |
    // bufA[(N+1)*64] f32 | bufB[(N+1)*64] f32
    // aliases in bufB: bpack [0,4MB), partial [4MB,12MB) — both dead before
    // layer-1 writes bufB. Zero rows live at row N_NODES (16.78MB) of each table.
    char* ws = (char*)d_ws;
    float* rs        = (float*)ws;                                 // [2N]
    float* rs_out    = rs;
    float* rs_in     = rs + N_NODES;
    int*   row_start = (int*)(rs + 2 * N_NODES);                   // [N+256]
    int*   block_h   = row_start + (N_NODES + 256);                // [65536]
    int*   so        = block_h + 256 * CHUNKS;                     // [65536]
    unsigned short* csr_src = (unsigned short*)(so + 256 * CHUNKS);// [E+16]
    float* bufA      = (float*)(csr_src + N_EDGES + 16);           // [(N+1)*64]
    float* bufB      = bufA + (size_t)(N_NODES + 1) * DIM;         // [(N+1)*64]
    int*      bpack   = (int*)bufB;                                // 4 MB
    unsigned* partial = (unsigned*)((char*)bufB + (size_t)4 * 1024 * 1024); // 8 MB
    float4* zeroA    = (float4*)(bufA + (size_t)N_NODES * DIM);    // row N_NODES
    float4* zeroB    = (float4*)(bufB + (size_t)N_NODES * DIM);

    const int fb = N_NODES / 16;      // 4096 blocks for fused layers

    edge_hist    <<<HB, 256, 0, stream>>>(src, dst, block_h, partial, zeroA, zeroB);
    part_scan    <<<1, 1024, 0, stream>>>(block_h, so);
    part_scatter <<<CHUNKS, 256, 0, stream>>>(src, dst, so, bpack);
    bucket_fused <<<256, 256, 0, stream>>>(bpack, so, row_start, rs_in, csr_src);
    oh2p_prescale<<<256, 256, 0, stream>>>(partial, rs_out, (const float4*)x, (float4*)bufA);

    // layers: bufA -> bufB(scaled) -> bufA(scaled) -> d_out (unscaled, no relu)
    fused_layer<true ><<<fb, 256, 0, stream>>>((const float4*)bufA, row_start, csr_src, rs_out, rs_in, W1, b1, (float4*)bufB);
    fused_layer<true ><<<fb, 256, 0, stream>>>((const float4*)bufB, row_start, csr_src, rs_out, rs_in, W2, b2, (float4*)bufA);
    fused_layer<false><<<fb, 256, 0, stream>>>((const float4*)bufA, row_start, csr_src, rs_out, rs_in, W3, b3, (float4*)out);
}

// Round 9
// 262.714 us; speedup vs baseline: 4.2096x; 1.1403x over previous
//
#include <hip/hip_runtime.h>
#include <hip/hip_fp16.h>

// GraphEncoder: 3x GraphConv(norm='both'), DIM=64, fixed graph.
// R9: inter-layer feature tables stored fp16 (8 MB vs 16 MB) -> halves the
// random-gather HBM demand and doubles effective L2 coverage. All arithmetic
// (aggregation accumulate, 64x64 matmul, norms) stays fp32; only storage of
// the prescaled propagated features is rounded. Final output fp32.

#define N_NODES 65536
#define N_EDGES 1048576
#define DIM 64

#define CHUNKS 256
#define EPC (N_EDGES / CHUNKS)        // 4096 edges per scatter chunk
#define HB 128                        // edge_hist blocks (2 chunks each)
#define OH_WORDS 16384                // 65536 nodes packed 4-per-word (64KB)

struct alignas(8) h4 { __half2 a, b; };   // 4 halves = 8 B

// --- one pass over edges: dst partition hist + packed src hist + zero rows ---
__global__ void edge_hist(const int* __restrict__ src, const int* __restrict__ dst,
                          int* __restrict__ block_hist, unsigned* __restrict__ partial,
                          uint2* __restrict__ zeroA, uint2* __restrict__ zeroB) {
    __shared__ unsigned h[OH_WORDS];  // 64 KB: src histogram, 8-bit x4 packed
    __shared__ int bh[2][256];
    int t = threadIdx.x;
    int j = blockIdx.x;               // 0..127
    for (int i = t; i < OH_WORDS; i += 256) h[i] = 0;
    bh[0][t] = 0; bh[1][t] = 0;
    __syncthreads();
    if (j == 0) {                     // zero row (row N_NODES, 128 B each table)
        if (t < 16) zeroA[t] = make_uint2(0u, 0u);
        else if (t < 32) zeroB[t - 16] = make_uint2(0u, 0u);
    }
    int base = j * (2 * EPC);
    for (int i = t; i < 2 * EPC; i += 256) {
        int s = src[base + i];
        int d = dst[base + i];
        atomicAdd(&h[s >> 2], 1u << ((s & 3) * 8));
        atomicAdd(&bh[i >> 12][d >> 8], 1);
    }
    __syncthreads();
    unsigned* dp = partial + (size_t)j * OH_WORDS;
    for (int i = t; i < OH_WORDS; i += 256) dp[i] = h[i];
    block_hist[t * CHUNKS + 2 * j]     = bh[0][t];
    block_hist[t * CHUNKS + 2 * j + 1] = bh[1][t];
}

// --- exclusive scan of 65536 (bucket-major [bucket][chunk]) ---
__global__ void part_scan(const int* __restrict__ bh, int* __restrict__ so) {
    __shared__ int s[1024];
    int t = threadIdx.x;
    const int4* b4 = (const int4*)(bh + t * 64);
    int4 v[16];
    int sum = 0;
    #pragma unroll
    for (int i = 0; i < 16; i++) {
        v[i] = b4[i];
        sum += v[i].x + v[i].y + v[i].z + v[i].w;
    }
    s[t] = sum;
    __syncthreads();
    for (int off = 1; off < 1024; off <<= 1) {
        int u = (t >= off) ? s[t - off] : 0;
        __syncthreads();
        s[t] += u;
        __syncthreads();
    }
    int run = s[t] - sum;
    int* o = so + t * 64;
    #pragma unroll
    for (int i = 0; i < 16; i++) {
        o[4 * i + 0] = run; run += v[i].x;
        o[4 * i + 1] = run; run += v[i].y;
        o[4 * i + 2] = run; run += v[i].z;
        o[4 * i + 3] = run; run += v[i].w;
    }
}

// --- scatter packed (src | dlow<<16) into bucket order, 256 chunks ---
__global__ void part_scatter(const int* __restrict__ src, const int* __restrict__ dst,
                             const int* __restrict__ so, int* __restrict__ bpack) {
    __shared__ int cur[256];
    cur[threadIdx.x] = so[threadIdx.x * CHUNKS + blockIdx.x];
    __syncthreads();
    int base = blockIdx.x * EPC;
    for (int i = threadIdx.x; i < EPC; i += 256) {
        int s = src[base + i];
        int d = dst[base + i];
        int pos = atomicAdd(&cur[d >> 8], 1);
        bpack[pos] = s | ((d & 255) << 16);
    }
}

// --- per-bucket (LDS-staged): hist -> scan -> row_start+rs_in -> csr emit ---
__global__ void bucket_fused(const int* __restrict__ bpack, const int* __restrict__ so,
                             int* __restrict__ row_start, float* __restrict__ rs_in,
                             unsigned short* __restrict__ csr_src) {
    __shared__ int stage[8192];                        // 32 KB
    __shared__ int h[256], sc[256], cur[256];
    int b = blockIdx.x;
    int t = threadIdx.x;
    int beg = so[b * CHUNKS];
    int end = (b == 255) ? N_EDGES : so[(b + 1) * CHUNKS];
    int n = end - beg;
    h[t] = 0;
    __syncthreads();
    for (int i = t; i < n; i += 256) {
        int p = bpack[beg + i];
        if (i < 8192) stage[i] = p;
        atomicAdd(&h[(p >> 16) & 255], 1);
    }
    __syncthreads();
    int d = h[t];
    sc[t] = d;
    __syncthreads();
    for (int off = 1; off < 256; off <<= 1) {
        int v = (t >= off) ? sc[t - off] : 0;
        __syncthreads();
        sc[t] += v;
        __syncthreads();
    }
    int rsv = beg + sc[t] - d;
    int node = b * 256 + t;
    row_start[node] = rsv;
    rs_in[node] = rsqrtf(d < 1 ? 1.0f : (float)d);
    if (node == N_NODES - 1) row_start[N_NODES] = N_EDGES;
    cur[t] = rsv;
    __syncthreads();
    for (int i = t; i < n; i += 256) {
        int p = (i < 8192) ? stage[i] : bpack[beg + i];
        int pos = atomicAdd(&cur[(p >> 16) & 255], 1);
        csr_src[pos] = (unsigned short)(p & 0xFFFF);
    }
}

// --- reduce src histograms -> rs_out, fused with fp16 prescale xs = x*rs_out ---
__global__ void oh2p_prescale(const unsigned* __restrict__ partial,
                              float* __restrict__ rs_out,
                              const float4* __restrict__ x4, h4* __restrict__ xs) {
    __shared__ float rsl[256];
    int b = blockIdx.x;
    int t = threadIdx.x;
    if (t < 64) {
        int w = b * 64 + t;
        int c0 = 0, c1 = 0, c2 = 0, c3 = 0;
        for (int c = 0; c < HB; c++) {
            unsigned v = partial[(size_t)c * OH_WORDS + w];
            c0 += (int)(v & 255u);
            c1 += (int)((v >> 8) & 255u);
            c2 += (int)((v >> 16) & 255u);
            c3 += (int)(v >> 24);
        }
        float4 r = make_float4(rsqrtf(c0 < 1 ? 1.0f : (float)c0),
                               rsqrtf(c1 < 1 ? 1.0f : (float)c1),
                               rsqrtf(c2 < 1 ? 1.0f : (float)c2),
                               rsqrtf(c3 < 1 ? 1.0f : (float)c3));
        ((float4*)rs_out)[w] = r;
        rsl[t * 4 + 0] = r.x; rsl[t * 4 + 1] = r.y;
        rsl[t * 4 + 2] = r.z; rsl[t * 4 + 3] = r.w;
    }
    __syncthreads();
    int rowbase = b * 256 * 16;                        // 4-elt units
    for (int i = t; i < 4096; i += 256) {
        float r = rsl[i >> 4];
        float4 v = x4[rowbase + i];
        h4 o;
        o.a = __float22half2_rn(make_float2(v.x * r, v.y * r));
        o.b = __float22half2_rn(make_float2(v.z * r, v.w * r));
        xs[rowbase + i] = o;
    }
}

// --- fused layer: 4 nodes/wave, 16 lanes/node, fp16 gather (8B/lane), fp32 math ---
template<bool SCALE_OUT>
__global__ void fused_layer(const h4* __restrict__ xs, const int* __restrict__ row_start,
                            const unsigned short* __restrict__ csr_src,
                            const float* __restrict__ rs_out, const float* __restrict__ rs_in,
                            const float* __restrict__ W, const float* __restrict__ b,
                            void* __restrict__ outp) {
    __shared__ float4 Ws4[DIM * 16];
    __shared__ float4 bs4[16];
    {
        const float4* Wg = (const float4*)W;
        for (int i = threadIdx.x; i < DIM * 16; i += blockDim.x) Ws4[i] = Wg[i];
        if (threadIdx.x < 16) bs4[threadIdx.x] = ((const float4*)b)[threadIdx.x];
    }
    __syncthreads();

    int wave_id = threadIdx.x >> 6;
    int lane = threadIdx.x & 63;
    int g = lane >> 4;
    int l = lane & 15;
    int node = blockIdx.x * 16 + wave_id * 4 + g;

    int beg = row_start[node];
    int end = row_start[node + 1];

    float4 acc = make_float4(0.f, 0.f, 0.f, 0.f);
    for (int k = beg; k < end; k += 16) {
        int s[16];
        #pragma unroll
        for (int j = 0; j < 16; j++) {
            int kk = k + j;
            int idx = csr_src[kk];                     // csr padded by 16 -> safe
            s[j] = (kk < end) ? idx : N_NODES;         // OOB -> zero row (L1-hot)
        }
        h4 v[16];
        #pragma unroll
        for (int j = 0; j < 16; j++) v[j] = xs[s[j] * 16 + l];
        #pragma unroll
        for (int j = 0; j < 16; j++) {
            float2 lo = __half22float2(v[j].a);
            float2 hi = __half22float2(v[j].b);
            acc.x += lo.x; acc.y += lo.y; acc.z += hi.x; acc.w += hi.y;
        }
    }
    float ri = rs_in[node];
    acc.x *= ri; acc.y *= ri; acc.z *= ri; acc.w *= ri;

    float4 o = bs4[l];
    int gbase = g << 4;
    #pragma unroll
    for (int m = 0; m < 16; m++) {
        float ax = __shfl(acc.x, gbase + m, 64);
        float ay = __shfl(acc.y, gbase + m, 64);
        float az = __shfl(acc.z, gbase + m, 64);
        float aw = __shfl(acc.w, gbase + m, 64);
        float4 w0 = Ws4[(4 * m + 0) * 16 + l];
        float4 w1 = Ws4[(4 * m + 1) * 16 + l];
        float4 w2 = Ws4[(4 * m + 2) * 16 + l];
        float4 w3 = Ws4[(4 * m + 3) * 16 + l];
        o.x += ax * w0.x + ay * w1.x + az * w2.x + aw * w3.x;
        o.y += ax * w0.y + ay * w1.y + az * w2.y + aw * w3.y;
        o.z += ax * w0.z + ay * w1.z + az * w2.z + aw * w3.z;
        o.w += ax * w0.w + ay * w1.w + az * w2.w + aw * w3.w;
    }
    if (SCALE_OUT) {
        float ro = rs_out[node];
        o.x = (o.x < 0.f ? 0.f : o.x) * ro;
        o.y = (o.y < 0.f ? 0.f : o.y) * ro;
        o.z = (o.z < 0.f ? 0.f : o.z) * ro;
        o.w = (o.w < 0.f ? 0.f : o.w) * ro;
        h4 ho;
        ho.a = __float22half2_rn(make_float2(o.x, o.y));
        ho.b = __float22half2_rn(make_float2(o.z, o.w));
        ((h4*)outp)[node * 16 + l] = ho;               // fp16 next-layer table
    } else {
        ((float4*)outp)[node * 16 + l] = o;            // fp32 final output
    }
}

extern "C" void kernel_launch(void* const* d_in, const int* in_sizes, int n_in,
                              void* d_out, int out_size, void* d_ws, size_t ws_size,
                              hipStream_t stream) {
    const float* x   = (const float*)d_in[0];
    const int*   ei  = (const int*)d_in[1];
    const int*   src = ei;
    const int*   dst = ei + N_EDGES;
    const float* W1 = (const float*)d_in[3];
    const float* b1 = (const float*)d_in[4];
    const float* W2 = (const float*)d_in[5];
    const float* b2 = (const float*)d_in[6];
    const float* W3 = (const float*)d_in[7];
    const float* b3 = (const float*)d_in[8];
    float* out = (float*)d_out;

    // workspace (~28 MB):
    // rs[2N] f32 | row_start[N+256] | block_hist[64K] | so[64K] | csr[E+16] u16 |
    // bufA[(N+1)*128B] fp16 | bufB[(N+1)*128B] fp16 | partial[8MB]
    // alias: bpack (4MB) over bufB head (dead before layer-1 writes bufB).
    char* ws = (char*)d_ws;
    float* rs        = (float*)ws;                                 // [2N]
    float* rs_out    = rs;
    float* rs_in     = rs + N_NODES;
    int*   row_start = (int*)(rs + 2 * N_NODES);                   // [N+256]
    int*   block_h   = row_start + (N_NODES + 256);                // [65536]
    int*   so        = block_h + 256 * CHUNKS;                     // [65536]
    unsigned short* csr_src = (unsigned short*)(so + 256 * CHUNKS);// [E+16]
    h4*    bufA      = (h4*)(csr_src + N_EDGES + 16);              // [(N+1)*16]
    h4*    bufB      = bufA + (size_t)(N_NODES + 1) * 16;          // [(N+1)*16]
    unsigned* partial = (unsigned*)(bufB + (size_t)(N_NODES + 1) * 16); // 8 MB
    int*   bpack     = (int*)bufB;                                 // 4 MB alias
    uint2* zeroA     = (uint2*)(bufA + (size_t)N_NODES * 16);      // row N_NODES
    uint2* zeroB     = (uint2*)(bufB + (size_t)N_NODES * 16);

    const int fb = N_NODES / 16;      // 4096 blocks for fused layers

    edge_hist    <<<HB, 256, 0, stream>>>(src, dst, block_h, partial, zeroA, zeroB);
    part_scan    <<<1, 1024, 0, stream>>>(block_h, so);
    part_scatter <<<CHUNKS, 256, 0, stream>>>(src, dst, so, bpack);
    bucket_fused <<<256, 256, 0, stream>>>(bpack, so, row_start, rs_in, csr_src);
    oh2p_prescale<<<256, 256, 0, stream>>>(partial, rs_out, (const float4*)x, bufA);

    // layers: bufA -> bufB(fp16, scaled) -> bufA(fp16, scaled) -> d_out (fp32)
    fused_layer<true ><<<fb, 256, 0, stream>>>(bufA, row_start, csr_src, rs_out, rs_in, W1, b1, (void*)bufB);
    fused_layer<true ><<<fb, 256, 0, stream>>>(bufB, row_start, csr_src, rs_out, rs_in, W2, b2, (void*)bufA);
    fused_layer<false><<<fb, 256, 0, stream>>>(bufA, row_start, csr_src, rs_out, rs_in, W3, b3, (void*)out);
}